// Round 10
// baseline (525.255 us; speedup 1.0000x reference)
//
#include <hip/hip_runtime.h>
#include <hip/hip_bf16.h>
#include <hip/hip_fp16.h>

// Problem constants
#define B_ 2
#define N_ 40962
#define D_ 128
#define H_ 4
#define P_ 100
#define S_ 512
#define T_ 102400      // B*P*S tokens
#define PS_ 51200      // P*S
#define CAP_ 32        // inverted-index capacity per node

typedef unsigned short u16;
typedef unsigned int u32;
typedef _Float16 f16x4 __attribute__((ext_vector_type(4)));
typedef _Float16 f16x8 __attribute__((ext_vector_type(8)));
typedef float f32x4 __attribute__((ext_vector_type(4)));

// Workspace byte offsets (total ~79.2 MB)
#define OFF_Q    0ull           // q fp16 [T][128]  (later reused as att)
#define OFF_K    26214400ull    // k fp16 per-head [bp*4+h][512][32]; reused as po[T][128] fp16 after attn
#define OFF_V    52428800ull    // v fp16 V^T [bp*4+h][32][512]; reused as cursor[N]+slots[N*32] after attn
#define OFF_BP   78643200ull    // packed W frags: 4 mats x 4096 lane-frags x 8B
#define OFF_CNT  78774272ull    // float cnt[N]
#define OFF_CM   78938120ull    // float cm[P*S]
#define OFF_FLAG 79142920ull    // int dtype flag for core_mask
#define CUR_BYTES ((size_t)N_ * 4)

__device__ __forceinline__ u32 pack2h(float a, float b) {
  __half2 h = __floats2half2_rn(a, b);
  return __builtin_bit_cast(u32, h);
}
__device__ __forceinline__ f16x8 cat8(uint2 lo, uint2 hi) {
  return __builtin_bit_cast(f16x8, make_uint4(lo.x, lo.y, hi.x, hi.y));
}

// 16x16x32 f16 MFMA; x32 frag = concat of two x16 half-frags (k 0..15, 16..31).
__device__ __forceinline__ f32x4 mfma32(f16x8 a, f16x8 b, f32x4 c) {
#if __has_builtin(__builtin_amdgcn_mfma_f32_16x16x32_f16)
  return __builtin_amdgcn_mfma_f32_16x16x32_f16(a, b, c, 0, 0, 0);
#else
  f16x4 alo = {a[0], a[1], a[2], a[3]}, ahi = {a[4], a[5], a[6], a[7]};
  f16x4 blo = {b[0], b[1], b[2], b[3]}, bhi = {b[4], b[5], b[6], b[7]};
  c = __builtin_amdgcn_mfma_f32_16x16x16f16(alo, blo, c, 0, 0, 0);
  return __builtin_amdgcn_mfma_f32_16x16x16f16(ahi, bhi, c, 0, 0, 0);
#endif
}

__device__ __forceinline__ bool mask_on(const void* mask, int fl, int i) {
  if (fl & 1) return ((const unsigned char*)mask)[i] != 0;
  if (fl & 2) return ((const float*)mask)[i] != 0.f;
  return ((const int*)mask)[i] != 0;
}

// ---------------------------------------------------------------------------
// Probe core_mask storage format (bool8 / int32 / float32); wave-reduced OR.
__global__ void probe_mask_k(const unsigned char* __restrict__ mb, int* __restrict__ flag) {
  int i = blockIdx.x * 256 + threadIdx.x;
  int f = 0;
  unsigned char v = mb[i];
  if (v) {
    int m4 = i & 3;
    if (m4 == 1) f |= 1;
    else if (m4 == 3) f |= 2;
  }
#pragma unroll
  for (int m = 32; m >= 1; m >>= 1) f |= __shfl_xor(f, m);
  if ((threadIdx.x & 63) == 0 && f) atomicOr(flag, f);
}

// cm[i] = mask as float; cnt[n] += cm
__global__ void mask_cnt_k(const void* __restrict__ mask, const int* __restrict__ pidx,
                           const int* __restrict__ flag, float* __restrict__ cm,
                           float* __restrict__ cnt) {
  int i = blockIdx.x * 256 + threadIdx.x;
  int fl = *flag;
  bool on = mask_on(mask, fl, i);
  cm[i] = on ? 1.f : 0.f;
  if (on) atomicAdd(&cnt[pidx[i]], 1.f);
}

// Build inverted index: for each masked slot ps, append to its node's list.
__global__ void fill_k(const void* __restrict__ mask, const int* __restrict__ pidx,
                       const int* __restrict__ flag, int* __restrict__ cursor,
                       int* __restrict__ slots) {
  int i = blockIdx.x * 256 + threadIdx.x;
  int fl = *flag;
  if (mask_on(mask, fl, i)) {
    int n = pidx[i];
    int pos = atomicAdd(&cursor[n], 1);
    if (pos < CAP_) slots[n * CAP_ + pos] = i;
  }
}

// ---------------------------------------------------------------------------
// Pack Wq/Wk/Wv/Wo into MFMA fragment order (fp16). Same bytes serve as
// B-operand (l15->n, 4*l4+i->k) and A-operand (l15->row n, 4*l4+i->k).
__global__ void pack_w_k(const float* __restrict__ Wq, const float* __restrict__ Wk,
                         const float* __restrict__ Wv, const float* __restrict__ Wo,
                         u16* __restrict__ bp) {
  int gi = blockIdx.x * 256 + threadIdx.x;   // < 16384
  int m = gi >> 12;
  int r = gi & 4095;
  int fi = r >> 6;         // nt*8 + ks
  int l = r & 63;
  int nt = fi >> 3, ks = fi & 7;
  const float* W = (m == 0) ? Wq : (m == 1) ? Wk : (m == 2) ? Wv : Wo;
  int n = nt * 16 + (l & 15);
  int k0 = ks * 16 + ((l >> 4) << 2);
  float4 w = *(const float4*)(W + n * 128 + k0);
  *(uint2*)(bp + (size_t)gi * 4) = make_uint2(pack2h(w.x, w.y), pack2h(w.z, w.w));
}

// ---------------------------------------------------------------------------
// QKV, barrier-free: each lane loads its MFMA A/B-fragments DIRECTLY from the
// gathered x row (8 independent float4 loads + cvt_pkrtz) — no LDS, no
// __syncthreads; waves fully decoupled. q,k use swapped operands (D'[n][t],
// verified round 7) -> uint2 stores; v original -> uint2 stores along s.
// mat 0 -> q [T][128]; mat 1 -> K [bp*4+h][512][32]; mat 2 -> V^T [bp*4+h][32][512].
__global__ __launch_bounds__(256) void qkv_k(
    const float* __restrict__ x, const int* __restrict__ pidx,
    const u16* __restrict__ bp,
    const float* __restrict__ bq, const float* __restrict__ bk, const float* __restrict__ bv,
    u16* __restrict__ qkv) {
  int tid = threadIdx.x;
  int t0 = blockIdx.x * 64;
  int lane = tid & 63, wid = tid >> 6;
  int l15 = lane & 15, l4 = lane >> 4;
  int wm = wid & 1, wn = wid >> 1;
  // direct global->reg X-frags for the wave's two 16-token tiles
  uint2 afr[2][8];
#pragma unroll
  for (int tt = 0; tt < 2; tt++) {
    int tok = t0 + wm * 32 + tt * 16 + l15;
    int b = (tok >= PS_) ? 1 : 0;
    int ps = tok - b * PS_;
    int pi = pidx[ps];
    const float* rp = x + ((size_t)b * N_ + pi) * D_;
#pragma unroll
    for (int ks = 0; ks < 8; ks++) {
      float4 f = *(const float4*)(rp + ks * 16 + l4 * 4);
      afr[tt][ks] = make_uint2(
          __builtin_bit_cast(u32, __builtin_amdgcn_cvt_pkrtz(f.x, f.y)),
          __builtin_bit_cast(u32, __builtin_amdgcn_cvt_pkrtz(f.z, f.w)));
    }
  }
  const uint2* bpp = (const uint2*)bp;
  u16* qout = qkv;
  u16* kh = qkv + (size_t)T_ * D_;
  u16* vt = qkv + (size_t)2 * T_ * D_;
#pragma unroll 1
  for (int mat = 0; mat < 3; mat++) {
    uint2 bfrag[4][8];
#pragma unroll
    for (int nt = 0; nt < 4; nt++) {
      int ntg = wn * 4 + nt;
#pragma unroll
      for (int ks = 0; ks < 8; ks++)
        bfrag[nt][ks] = bpp[(mat * 64 + ntg * 8 + ks) * 64 + lane];
    }
    if (mat < 2) {
      // SWAPPED: D'[n][t]; lane: t = wm*32+tt*16+l15, n = wn*64+nt*16+4*l4+i
      const float* bias = (mat == 0) ? bq : bk;
      f32x4 acc[4][2];
#pragma unroll
      for (int nt = 0; nt < 4; nt++) {
        float4 b4 = *(const float4*)(bias + wn * 64 + nt * 16 + l4 * 4);
        f32x4 bz = {b4.x, b4.y, b4.z, b4.w};
        acc[nt][0] = bz;
        acc[nt][1] = bz;
      }
#pragma unroll
      for (int kp = 0; kp < 4; kp++) {
#pragma unroll
        for (int nt = 0; nt < 4; nt++) {
          f16x8 a = cat8(bfrag[nt][2 * kp], bfrag[nt][2 * kp + 1]);
#pragma unroll
          for (int tt = 0; tt < 2; tt++) {
            f16x8 b = cat8(afr[tt][2 * kp], afr[tt][2 * kp + 1]);
            acc[nt][tt] = mfma32(a, b, acc[nt][tt]);
          }
        }
      }
#pragma unroll
      for (int tt = 0; tt < 2; tt++) {
        int tok = t0 + wm * 32 + tt * 16 + l15;
#pragma unroll
        for (int nt = 0; nt < 4; nt++) {
          int n0 = wn * 64 + nt * 16 + l4 * 4;
          f32x4 a = acc[nt][tt];
          uint2 pv = make_uint2(pack2h(a[0], a[1]), pack2h(a[2], a[3]));
          if (mat == 0) {
            *(uint2*)(qout + (size_t)tok * D_ + n0) = pv;
          } else {
            int bpi = tok >> 9, s = tok & 511;
            int ch = n0 >> 5, hd = n0 & 31;
            *(uint2*)(kh + ((size_t)(bpi * 4 + ch) * 512 + s) * 32 + hd) = pv;
          }
        }
      }
    } else {
      // ORIGINAL: D[t][n]; lane: t = wm*32+mt*16+4*l4+i, n = wn*64+nt*16+l15
      f32x4 acc[2][4];
#pragma unroll
      for (int nt = 0; nt < 4; nt++) {
        float bvv = bv[wn * 64 + nt * 16 + l15];
#pragma unroll
        for (int mt = 0; mt < 2; mt++) {
          f32x4 z = {bvv, bvv, bvv, bvv};
          acc[mt][nt] = z;
        }
      }
#pragma unroll
      for (int kp = 0; kp < 4; kp++) {
#pragma unroll
        for (int mt = 0; mt < 2; mt++) {
          f16x8 a = cat8(afr[mt][2 * kp], afr[mt][2 * kp + 1]);
#pragma unroll
          for (int nt = 0; nt < 4; nt++) {
            f16x8 b = cat8(bfrag[nt][2 * kp], bfrag[nt][2 * kp + 1]);
            acc[mt][nt] = mfma32(a, b, acc[mt][nt]);
          }
        }
      }
#pragma unroll
      for (int mt = 0; mt < 2; mt++) {
        int rbase = t0 + wm * 32 + mt * 16 + (l4 << 2);
        int bpi = rbase >> 9;
        int s0 = rbase & 511;
#pragma unroll
        for (int nt = 0; nt < 4; nt++) {
          int col = wn * 64 + nt * 16 + l15;
          uint2 pv = make_uint2(pack2h(acc[mt][nt][0], acc[mt][nt][1]),
                                pack2h(acc[mt][nt][2], acc[mt][nt][3]));
          *(uint2*)(vt + ((size_t)(bpi * 4 + (col >> 5)) * 32 + (col & 31)) * 512 + s0) = pv;
        }
      }
    }
  }
}

// ---------------------------------------------------------------------------
// MFMA flash-attention, swapped operands, x32 MFMA. One block = (bp, h),
// 512 threads / 8 waves. Only V^T staged in LDS (32 KB -> 4 blocks/CU);
// K fragments read directly from L2-resident global. Single barrier.
__global__ __launch_bounds__(512, 8) void attn_k(
    u16* wq_att, const u16* __restrict__ wk, const u16* __restrict__ wvt) {
  __shared__ __align__(16) u16 Vs[32 * 512];  // [hd][512 k], 8B-granule swizzle
  int tid = threadIdx.x;
  int bid = blockIdx.x;
  int h = bid & 3;
  int bp = bid >> 2;
  int lane = tid & 63, w = tid >> 6;
  int l15 = lane & 15, l4 = lane >> 4;
  size_t tbase = (size_t)bp * 512;
  int q0 = w * 64;
  const u16* kg = wk + (size_t)(bp * 4 + h) * 512 * 32;
  // stage V^T (contiguous 32 KB)
  {
    const u16* vg = wvt + (size_t)(bp * 4 + h) * 32 * 512;
#pragma unroll
    for (int j = 0; j < 4; j++) {
      int i = j * 512 + tid;
      uint4 vu = *(const uint4*)(vg + (size_t)i * 8);
      int vr2 = i >> 6, vc = i & 63;
      int swv = vr2 & 15;
      *(uint2*)(Vs + vr2 * 512 + (((2 * vc)     ^ swv) << 2)) = make_uint2(vu.x, vu.y);
      *(uint2*)(Vs + vr2 * 512 + (((2 * vc + 1) ^ swv) << 2)) = make_uint2(vu.z, vu.w);
    }
  }
  // Q B-frags (x32), pre-scaled by log2(e)/sqrt(32).
  uint4 qf8[4];
  {
    const u16* qbase = wq_att + (tbase + q0) * 128 + h * 32;
    const __half2 sc2 = __floats2half2_rn(0.25500527f, 0.25500527f);
#pragma unroll
    for (int nt = 0; nt < 4; nt++) {
      const u16* qr = qbase + (size_t)(nt * 16 + l15) * 128 + l4 * 4;
      uint2 u0 = *(const uint2*)(qr);
      uint2 u1 = *(const uint2*)(qr + 16);
      u32 w0 = __builtin_bit_cast(u32, __hmul2(__builtin_bit_cast(__half2, u0.x), sc2));
      u32 w1 = __builtin_bit_cast(u32, __hmul2(__builtin_bit_cast(__half2, u0.y), sc2));
      u32 w2 = __builtin_bit_cast(u32, __hmul2(__builtin_bit_cast(__half2, u1.x), sc2));
      u32 w3 = __builtin_bit_cast(u32, __hmul2(__builtin_bit_cast(__half2, u1.y), sc2));
      qf8[nt] = make_uint4(w0, w1, w2, w3);
    }
  }
  f32x4 O[2][4];
  f32x4 LS[4];
#pragma unroll
  for (int a = 0; a < 4; a++) {
    O[0][a] = (f32x4){0.f, 0.f, 0.f, 0.f};
    O[1][a] = (f32x4){0.f, 0.f, 0.f, 0.f};
    LS[a] = (f32x4){0.f, 0.f, 0.f, 0.f};
  }
  const f16x8 ones8 = {(_Float16)1.f, (_Float16)1.f, (_Float16)1.f, (_Float16)1.f,
                       (_Float16)1.f, (_Float16)1.f, (_Float16)1.f, (_Float16)1.f};
  __syncthreads();   // the only barrier (V staging)

  for (int t0 = 0; t0 < 512; t0 += 64) {
#pragma unroll
    for (int mp = 0; mp < 2; mp++) {
      // K x32 A-frags straight from global (L2-hot)
      const u16* kpA = kg + (size_t)(t0 + mp * 32 + l15) * 32;
      const u16* kpB = kpA + 16 * 32;
      uint2 a0A = *(const uint2*)(kpA + l4 * 4);
      uint2 a1A = *(const uint2*)(kpA + 16 + l4 * 4);
      uint2 a0B = *(const uint2*)(kpB + l4 * 4);
      uint2 a1B = *(const uint2*)(kpB + 16 + l4 * 4);
      f16x8 a8A = cat8(a0A, a1A);
      f16x8 a8B = cat8(a0B, a1B);
      int gA = (t0 >> 2) + mp * 8 + l4;
      int gB = gA + 4;
      uint2 vA0 = *(const uint2*)(Vs + l15 * 512        + ((gA ^ l15) << 2));
      uint2 vB0 = *(const uint2*)(Vs + l15 * 512        + ((gB ^ l15) << 2));
      uint2 vA1 = *(const uint2*)(Vs + (16 + l15) * 512 + ((gA ^ l15) << 2));
      uint2 vB1 = *(const uint2*)(Vs + (16 + l15) * 512 + ((gB ^ l15) << 2));
      f16x8 v80 = cat8(vA0, vB0);
      f16x8 v81 = cat8(vA1, vB1);
      __builtin_amdgcn_s_setprio(1);
#pragma unroll
      for (int nt = 0; nt < 4; nt++) {
        f16x8 qb = __builtin_bit_cast(f16x8, qf8[nt]);
        f32x4 z = {0.f, 0.f, 0.f, 0.f};
        f32x4 sA = mfma32(a8A, qb, z);
        f32x4 sB = mfma32(a8B, qb, z);
        float e0 = __builtin_amdgcn_exp2f(sA[0]);
        float e1 = __builtin_amdgcn_exp2f(sA[1]);
        float e2 = __builtin_amdgcn_exp2f(sA[2]);
        float e3 = __builtin_amdgcn_exp2f(sA[3]);
        float e4 = __builtin_amdgcn_exp2f(sB[0]);
        float e5 = __builtin_amdgcn_exp2f(sB[1]);
        float e6 = __builtin_amdgcn_exp2f(sB[2]);
        float e7 = __builtin_amdgcn_exp2f(sB[3]);
        uint4 pu = make_uint4(
            __builtin_bit_cast(u32, __builtin_amdgcn_cvt_pkrtz(e0, e1)),
            __builtin_bit_cast(u32, __builtin_amdgcn_cvt_pkrtz(e2, e3)),
            __builtin_bit_cast(u32, __builtin_amdgcn_cvt_pkrtz(e4, e5)),
            __builtin_bit_cast(u32, __builtin_amdgcn_cvt_pkrtz(e6, e7)));
        f16x8 pb = __builtin_bit_cast(f16x8, pu);
        LS[nt]   = mfma32(ones8, pb, LS[nt]);
        O[0][nt] = mfma32(v80, pb, O[0][nt]);
        O[1][nt] = mfma32(v81, pb, O[1][nt]);
      }
      __builtin_amdgcn_s_setprio(0);
    }
  }
  // store att (overwrites this block's own q-rows / h-col slice only)
#pragma unroll
  for (int nt = 0; nt < 4; nt++) {
    float r = 1.f / LS[nt][0];
#pragma unroll
    for (int mt2 = 0; mt2 < 2; mt2++) {
      uint2 ov = make_uint2(pack2h(O[mt2][nt][0] * r, O[mt2][nt][1] * r),
                            pack2h(O[mt2][nt][2] * r, O[mt2][nt][3] * r));
      *(uint2*)(wq_att + (tbase + q0 + nt * 16 + l15) * 128 + h * 32 + mt2 * 16 + l4 * 4) = ov;
    }
  }
}

// ---------------------------------------------------------------------------
// Output projection, SWAPPED operands: D'[n][t], lane holds 4 consecutive n
// for one token -> dense uint2 stores of (att @ Wo^T + bo) into po[T][128].
// No mask, no atomics: masked slots are simply never gathered by ln_k.
__global__ __launch_bounds__(256) void proj_k(
    const u16* __restrict__ watt, const u16* __restrict__ bp, const float* __restrict__ bo,
    u16* __restrict__ po) {
  __shared__ uint4 As[64 * 16];
  int tid = threadIdx.x;
  int t0 = blockIdx.x * 64;
  {
    int r = tid >> 2, qd = tid & 3;
    const uint4* src = (const uint4*)(watt + (size_t)(t0 + r) * D_ + qd * 32);
#pragma unroll
    for (int c = 0; c < 4; c++) {
      int byteoff = (qd * 64 + c * 16) ^ ((r & 7) << 4);
      As[r * 16 + (byteoff >> 4)] = src[c];
    }
  }
  __syncthreads();
  int lane = tid & 63, wid = tid >> 6;
  int l15 = lane & 15, l4 = lane >> 4;
  int wm = wid & 1, wn = wid >> 1;
  uint2 bfrag[4][8];
  const uint2* bpp = (const uint2*)bp;
#pragma unroll
  for (int nt = 0; nt < 4; nt++) {
    int ntg = wn * 4 + nt;
#pragma unroll
    for (int ks = 0; ks < 8; ks++)
      bfrag[nt][ks] = bpp[(3 * 64 + ntg * 8 + ks) * 64 + lane];
  }
  uint2 afr[2][8];
#pragma unroll
  for (int tt = 0; tt < 2; tt++) {
    int row = wm * 32 + tt * 16 + l15;
#pragma unroll
    for (int ks = 0; ks < 8; ks++) {
      int byteoff = (ks * 32 + (l4 << 3)) ^ ((row & 7) << 4);
      afr[tt][ks] = *(const uint2*)((const char*)As + row * 256 + byteoff);
    }
  }
  // acc[nt][tt]: D'[n][t], n = wn*64+nt*16+4*l4+i, t = wm*32+tt*16+l15
  f32x4 acc[4][2];
#pragma unroll
  for (int nt = 0; nt < 4; nt++) {
    float4 bo4 = *(const float4*)(bo + wn * 64 + nt * 16 + l4 * 4);
    f32x4 bz = {bo4.x, bo4.y, bo4.z, bo4.w};
    acc[nt][0] = bz;
    acc[nt][1] = bz;
  }
#pragma unroll
  for (int kp = 0; kp < 4; kp++) {
#pragma unroll
    for (int nt = 0; nt < 4; nt++) {
      f16x8 a = cat8(bfrag[nt][2 * kp], bfrag[nt][2 * kp + 1]);
#pragma unroll
      for (int tt = 0; tt < 2; tt++) {
        f16x8 b = cat8(afr[tt][2 * kp], afr[tt][2 * kp + 1]);
        acc[nt][tt] = mfma32(a, b, acc[nt][tt]);
      }
    }
  }
#pragma unroll
  for (int tt = 0; tt < 2; tt++) {
    size_t tok = t0 + wm * 32 + tt * 16 + l15;
#pragma unroll
    for (int nt = 0; nt < 4; nt++) {
      int n0 = wn * 64 + nt * 16 + l4 * 4;
      f32x4 a = acc[nt][tt];
      uint2 pv = make_uint2(pack2h(a[0], a[1]), pack2h(a[2], a[3]));
      *(uint2*)(po + tok * D_ + n0) = pv;
    }
  }
}

// ---------------------------------------------------------------------------
// Gather-aggregate + residual + LayerNorm. Per (b,n) row: sum deg=cnt[n]
// po rows (fp32 accum), h = x + sum/max(cnt,1), LN over D.
__global__ __launch_bounds__(256) void ln_k(
    const float* __restrict__ x, const float* __restrict__ cnt,
    const u16* __restrict__ po, const int* __restrict__ slots,
    const float* __restrict__ g, const float* __restrict__ bta, float* __restrict__ out) {
  int tid = threadIdx.x;
  int row = blockIdx.x * 8 + (tid >> 5);
  if (row >= B_ * N_) return;
  int l32 = tid & 31;
  int n = row % N_;
  int b = row / N_;
  float c = cnt[n];
  int deg = (int)c;
  if (deg > CAP_) deg = CAP_;
  float rc = 1.f / (c > 1.f ? c : 1.f);
  float4 a = make_float4(0.f, 0.f, 0.f, 0.f);
  const int* sl = slots + n * CAP_;
  for (int j = 0; j < deg; j++) {
    int s = sl[j];
    uint2 u = *(const uint2*)(po + ((size_t)b * PS_ + s) * D_ + l32 * 4);
    float2 a01 = __half22float2(__builtin_bit_cast(__half2, u.x));
    float2 a23 = __half22float2(__builtin_bit_cast(__half2, u.y));
    a.x += a01.x; a.y += a01.y; a.z += a23.x; a.w += a23.y;
  }
  size_t off = (size_t)row * D_ + l32 * 4;
  float4 xa = *(const float4*)(x + off);
  float4 hv = make_float4(fmaf(a.x, rc, xa.x), fmaf(a.y, rc, xa.y),
                          fmaf(a.z, rc, xa.z), fmaf(a.w, rc, xa.w));
  float s = hv.x + hv.y + hv.z + hv.w;
  float s2 = hv.x * hv.x + hv.y * hv.y + hv.z * hv.z + hv.w * hv.w;
#pragma unroll
  for (int m = 16; m >= 1; m >>= 1) {
    s += __shfl_xor(s, m);
    s2 += __shfl_xor(s2, m);
  }
  float mu = s * 0.0078125f;
  float var = s2 * 0.0078125f - mu * mu;
  float rstd = rsqrtf(var + 1e-5f);
  float4 gv = *(const float4*)(g + l32 * 4);
  float4 bv = *(const float4*)(bta + l32 * 4);
  float4 ov = make_float4((hv.x - mu) * rstd * gv.x + bv.x,
                          (hv.y - mu) * rstd * gv.y + bv.y,
                          (hv.z - mu) * rstd * gv.z + bv.z,
                          (hv.w - mu) * rstd * gv.w + bv.w);
  *(float4*)(out + off) = ov;
}

// ---------------------------------------------------------------------------
extern "C" void kernel_launch(void* const* d_in, const int* in_sizes, int n_in,
                              void* d_out, int out_size, void* d_ws, size_t ws_size,
                              hipStream_t stream) {
  const float* x   = (const float*)d_in[0];
  const float* Wq  = (const float*)d_in[1];
  const float* bq  = (const float*)d_in[2];
  const float* Wk  = (const float*)d_in[3];
  const float* bk  = (const float*)d_in[4];
  const float* Wv  = (const float*)d_in[5];
  const float* bv  = (const float*)d_in[6];
  const float* Wo  = (const float*)d_in[7];
  const float* bo  = (const float*)d_in[8];
  const float* lng = (const float*)d_in[9];
  const float* lnb = (const float*)d_in[10];
  const int* pidx  = (const int*)d_in[11];
  const void* cmask = d_in[12];
  float* out = (float*)d_out;
  char* ws = (char*)d_ws;

  u16* wsq = (u16*)(ws + OFF_Q);
  u16* wsk = (u16*)(ws + OFF_K);
  u16* wsvt = (u16*)(ws + OFF_V);
  u16* wbp = (u16*)(ws + OFF_BP);
  float* wcnt = (float*)(ws + OFF_CNT);
  float* wcm  = (float*)(ws + OFF_CM);
  int* wflag  = (int*)(ws + OFF_FLAG);
  // after attn: K region -> po[T][128] fp16; V region -> cursor[N] + slots[N*CAP]
  u16* po = (u16*)(ws + OFF_K);
  int* cursor = (int*)(ws + OFF_V);
  int* slots = (int*)(ws + OFF_V + CUR_BYTES);

  hipMemsetAsync(ws + OFF_CNT, 0, (OFF_FLAG + 4) - OFF_CNT, stream);

  probe_mask_k<<<200, 256, 0, stream>>>((const unsigned char*)cmask, wflag);
  mask_cnt_k<<<200, 256, 0, stream>>>(cmask, pidx, wflag, wcm, wcnt);
  pack_w_k<<<64, 256, 0, stream>>>(Wq, Wk, Wv, Wo, wbp);
  qkv_k<<<1600, 256, 0, stream>>>(x, pidx, wbp, bq, bk, bv, wsq);
  attn_k<<<800, 512, 0, stream>>>(wsq, wsk, wsvt);
  // V region dead: build inverted index there
  hipMemsetAsync(cursor, 0, CUR_BYTES, stream);
  fill_k<<<200, 256, 0, stream>>>(cmask, pidx, wflag, cursor, slots);
  proj_k<<<1600, 256, 0, stream>>>(wsq, wbp, bo, po);
  ln_k<<<10241, 256, 0, stream>>>(x, wcnt, po, slots, lng, lnb, out);
}

// Round 11
// 163.466 us; speedup vs baseline: 3.2132x; 3.2132x over previous
//
#include <hip/hip_runtime.h>
#include <hip/hip_bf16.h>
#include <hip/hip_fp16.h>

// Problem constants
#define B_ 2
#define N_ 40962
#define D_ 128
#define H_ 4
#define P_ 100
#define S_ 512
#define T_ 102400      // B*P*S tokens
#define PS_ 51200      // P*S
#define CAP_ 32        // inverted-index capacity per node

typedef unsigned short u16;
typedef unsigned int u32;
typedef _Float16 f16x4 __attribute__((ext_vector_type(4)));
typedef _Float16 f16x8 __attribute__((ext_vector_type(8)));
typedef float f32x4 __attribute__((ext_vector_type(4)));

// Workspace byte offsets (total ~79.2 MB)
#define OFF_Q    0ull           // q fp16 [T][128]  (later reused as att)
#define OFF_K    26214400ull    // k fp16 per-head [bp*4+h][512][32]; reused as po[T][128] fp16 after attn
#define OFF_V    52428800ull    // v fp16 V^T [bp*4+h][32][512]; reused as cursor[N]+slots[N*32] after attn
#define OFF_BP   78643200ull    // packed W frags: 4 mats x 4096 lane-frags x 8B
#define OFF_CNT  78774272ull    // float cnt[N]
#define OFF_CM   78938120ull    // float cm[P*S]
#define OFF_FLAG 79142920ull    // int dtype flag for core_mask
#define CUR_BYTES ((size_t)N_ * 4)

__device__ __forceinline__ u32 pack2h(float a, float b) {
  __half2 h = __floats2half2_rn(a, b);
  return __builtin_bit_cast(u32, h);
}
__device__ __forceinline__ f16x8 cat8(uint2 lo, uint2 hi) {
  return __builtin_bit_cast(f16x8, make_uint4(lo.x, lo.y, hi.x, hi.y));
}

// 16x16x32 f16 MFMA; x32 frag = concat of two x16 half-frags (k 0..15, 16..31).
__device__ __forceinline__ f32x4 mfma32(f16x8 a, f16x8 b, f32x4 c) {
#if __has_builtin(__builtin_amdgcn_mfma_f32_16x16x32_f16)
  return __builtin_amdgcn_mfma_f32_16x16x32_f16(a, b, c, 0, 0, 0);
#else
  f16x4 alo = {a[0], a[1], a[2], a[3]}, ahi = {a[4], a[5], a[6], a[7]};
  f16x4 blo = {b[0], b[1], b[2], b[3]}, bhi = {b[4], b[5], b[6], b[7]};
  c = __builtin_amdgcn_mfma_f32_16x16x16f16(alo, blo, c, 0, 0, 0);
  return __builtin_amdgcn_mfma_f32_16x16x16f16(ahi, bhi, c, 0, 0, 0);
#endif
}

__device__ __forceinline__ bool mask_on(const void* mask, int fl, int i) {
  if (fl & 1) return ((const unsigned char*)mask)[i] != 0;
  if (fl & 2) return ((const float*)mask)[i] != 0.f;
  return ((const int*)mask)[i] != 0;
}

// ---------------------------------------------------------------------------
// Probe core_mask storage format (bool8 / int32 / float32); wave-reduced OR.
__global__ void probe_mask_k(const unsigned char* __restrict__ mb, int* __restrict__ flag) {
  int i = blockIdx.x * 256 + threadIdx.x;
  int f = 0;
  unsigned char v = mb[i];
  if (v) {
    int m4 = i & 3;
    if (m4 == 1) f |= 1;
    else if (m4 == 3) f |= 2;
  }
#pragma unroll
  for (int m = 32; m >= 1; m >>= 1) f |= __shfl_xor(f, m);
  if ((threadIdx.x & 63) == 0 && f) atomicOr(flag, f);
}

// cm[i] = mask as float; cnt[n] += cm
__global__ void mask_cnt_k(const void* __restrict__ mask, const int* __restrict__ pidx,
                           const int* __restrict__ flag, float* __restrict__ cm,
                           float* __restrict__ cnt) {
  int i = blockIdx.x * 256 + threadIdx.x;
  int fl = *flag;
  bool on = mask_on(mask, fl, i);
  cm[i] = on ? 1.f : 0.f;
  if (on) atomicAdd(&cnt[pidx[i]], 1.f);
}

// Build inverted index: for each masked slot ps, append to its node's list.
__global__ void fill_k(const void* __restrict__ mask, const int* __restrict__ pidx,
                       const int* __restrict__ flag, int* __restrict__ cursor,
                       int* __restrict__ slots) {
  int i = blockIdx.x * 256 + threadIdx.x;
  int fl = *flag;
  if (mask_on(mask, fl, i)) {
    int n = pidx[i];
    int pos = atomicAdd(&cursor[n], 1);
    if (pos < CAP_) slots[n * CAP_ + pos] = i;
  }
}

// ---------------------------------------------------------------------------
// Pack Wq/Wk/Wv/Wo into MFMA fragment order (fp16). Same bytes serve as
// B-operand (l15->n, 4*l4+i->k) and A-operand (l15->row n, 4*l4+i->k).
__global__ void pack_w_k(const float* __restrict__ Wq, const float* __restrict__ Wk,
                         const float* __restrict__ Wv, const float* __restrict__ Wo,
                         u16* __restrict__ bp) {
  int gi = blockIdx.x * 256 + threadIdx.x;   // < 16384
  int m = gi >> 12;
  int r = gi & 4095;
  int fi = r >> 6;         // nt*8 + ks
  int l = r & 63;
  int nt = fi >> 3, ks = fi & 7;
  const float* W = (m == 0) ? Wq : (m == 1) ? Wk : (m == 2) ? Wv : Wo;
  int n = nt * 16 + (l & 15);
  int k0 = ks * 16 + ((l >> 4) << 2);
  float4 w = *(const float4*)(W + n * 128 + k0);
  *(uint2*)(bp + (size_t)gi * 4) = make_uint2(pack2h(w.x, w.y), pack2h(w.z, w.w));
}

// ---------------------------------------------------------------------------
// QKV, barrier-free (round-10, proven): each lane loads its MFMA fragments
// DIRECTLY from the gathered x row — no LDS, no __syncthreads. q,k swapped
// (D'[n][t]) -> uint2 stores; v original -> uint2 stores along s.
// mat 0 -> q [T][128]; mat 1 -> K [bp*4+h][512][32]; mat 2 -> V^T [bp*4+h][32][512].
__global__ __launch_bounds__(256) void qkv_k(
    const float* __restrict__ x, const int* __restrict__ pidx,
    const u16* __restrict__ bp,
    const float* __restrict__ bq, const float* __restrict__ bk, const float* __restrict__ bv,
    u16* __restrict__ qkv) {
  int tid = threadIdx.x;
  int t0 = blockIdx.x * 64;
  int lane = tid & 63, wid = tid >> 6;
  int l15 = lane & 15, l4 = lane >> 4;
  int wm = wid & 1, wn = wid >> 1;
  // direct global->reg X-frags for the wave's two 16-token tiles
  uint2 afr[2][8];
#pragma unroll
  for (int tt = 0; tt < 2; tt++) {
    int tok = t0 + wm * 32 + tt * 16 + l15;
    int b = (tok >= PS_) ? 1 : 0;
    int ps = tok - b * PS_;
    int pi = pidx[ps];
    const float* rp = x + ((size_t)b * N_ + pi) * D_;
#pragma unroll
    for (int ks = 0; ks < 8; ks++) {
      float4 f = *(const float4*)(rp + ks * 16 + l4 * 4);
      afr[tt][ks] = make_uint2(
          __builtin_bit_cast(u32, __builtin_amdgcn_cvt_pkrtz(f.x, f.y)),
          __builtin_bit_cast(u32, __builtin_amdgcn_cvt_pkrtz(f.z, f.w)));
    }
  }
  const uint2* bpp = (const uint2*)bp;
  u16* qout = qkv;
  u16* kh = qkv + (size_t)T_ * D_;
  u16* vt = qkv + (size_t)2 * T_ * D_;
#pragma unroll 1
  for (int mat = 0; mat < 3; mat++) {
    uint2 bfrag[4][8];
#pragma unroll
    for (int nt = 0; nt < 4; nt++) {
      int ntg = wn * 4 + nt;
#pragma unroll
      for (int ks = 0; ks < 8; ks++)
        bfrag[nt][ks] = bpp[(mat * 64 + ntg * 8 + ks) * 64 + lane];
    }
    if (mat < 2) {
      // SWAPPED: D'[n][t]; lane: t = wm*32+tt*16+l15, n = wn*64+nt*16+4*l4+i
      const float* bias = (mat == 0) ? bq : bk;
      f32x4 acc[4][2];
#pragma unroll
      for (int nt = 0; nt < 4; nt++) {
        float4 b4 = *(const float4*)(bias + wn * 64 + nt * 16 + l4 * 4);
        f32x4 bz = {b4.x, b4.y, b4.z, b4.w};
        acc[nt][0] = bz;
        acc[nt][1] = bz;
      }
#pragma unroll
      for (int kp = 0; kp < 4; kp++) {
#pragma unroll
        for (int nt = 0; nt < 4; nt++) {
          f16x8 a = cat8(bfrag[nt][2 * kp], bfrag[nt][2 * kp + 1]);
#pragma unroll
          for (int tt = 0; tt < 2; tt++) {
            f16x8 b = cat8(afr[tt][2 * kp], afr[tt][2 * kp + 1]);
            acc[nt][tt] = mfma32(a, b, acc[nt][tt]);
          }
        }
      }
#pragma unroll
      for (int tt = 0; tt < 2; tt++) {
        int tok = t0 + wm * 32 + tt * 16 + l15;
#pragma unroll
        for (int nt = 0; nt < 4; nt++) {
          int n0 = wn * 64 + nt * 16 + l4 * 4;
          f32x4 a = acc[nt][tt];
          uint2 pv = make_uint2(pack2h(a[0], a[1]), pack2h(a[2], a[3]));
          if (mat == 0) {
            *(uint2*)(qout + (size_t)tok * D_ + n0) = pv;
          } else {
            int bpi = tok >> 9, s = tok & 511;
            int ch = n0 >> 5, hd = n0 & 31;
            *(uint2*)(kh + ((size_t)(bpi * 4 + ch) * 512 + s) * 32 + hd) = pv;
          }
        }
      }
    } else {
      // ORIGINAL: D[t][n]; lane: t = wm*32+mt*16+4*l4+i, n = wn*64+nt*16+l15
      f32x4 acc[2][4];
#pragma unroll
      for (int nt = 0; nt < 4; nt++) {
        float bvv = bv[wn * 64 + nt * 16 + l15];
#pragma unroll
        for (int mt = 0; mt < 2; mt++) {
          f32x4 z = {bvv, bvv, bvv, bvv};
          acc[mt][nt] = z;
        }
      }
#pragma unroll
      for (int kp = 0; kp < 4; kp++) {
#pragma unroll
        for (int mt = 0; mt < 2; mt++) {
          f16x8 a = cat8(afr[mt][2 * kp], afr[mt][2 * kp + 1]);
#pragma unroll
          for (int nt = 0; nt < 4; nt++) {
            f16x8 b = cat8(bfrag[nt][2 * kp], bfrag[nt][2 * kp + 1]);
            acc[mt][nt] = mfma32(a, b, acc[mt][nt]);
          }
        }
      }
#pragma unroll
      for (int mt = 0; mt < 2; mt++) {
        int rbase = t0 + wm * 32 + mt * 16 + (l4 << 2);
        int bpi = rbase >> 9;
        int s0 = rbase & 511;
#pragma unroll
        for (int nt = 0; nt < 4; nt++) {
          int col = wn * 64 + nt * 16 + l15;
          uint2 pv = make_uint2(pack2h(acc[mt][nt][0], acc[mt][nt][1]),
                                pack2h(acc[mt][nt][2], acc[mt][nt][3]));
          *(uint2*)(vt + ((size_t)(bpi * 4 + (col >> 5)) * 32 + (col & 31)) * 512 + s0) = pv;
        }
      }
    }
  }
}

// ---------------------------------------------------------------------------
// MFMA flash-attention (round-9 proven version): swapped operands, x32 MFMA.
// One block = (bp, h), 512 threads / 8 waves. Whole K (512x32) and V^T
// (32x512) staged in LDS once (64 KB) -> single barrier; waves free-run.
__global__ __launch_bounds__(512, 4) void attn_k(
    u16* wq_att, const u16* __restrict__ wk, const u16* __restrict__ wvt) {
  __shared__ __align__(16) u16 Ks[512 * 32];  // [k][32 hd], 8B-granule swizzle
  __shared__ __align__(16) u16 Vs[32 * 512];  // [hd][512 k], 8B-granule swizzle
  int tid = threadIdx.x;
  int bid = blockIdx.x;
  int h = bid & 3;
  int bp = bid >> 2;
  int lane = tid & 63, w = tid >> 6;
  int l15 = lane & 15, l4 = lane >> 4;
  size_t tbase = (size_t)bp * 512;
  int q0 = w * 64;
  // stage whole K (contiguous per-head) and V^T (contiguous)
  {
    const u16* kg = wk + (size_t)(bp * 4 + h) * 512 * 32;
    const u16* vg = wvt + (size_t)(bp * 4 + h) * 32 * 512;
#pragma unroll
    for (int j = 0; j < 4; j++) {
      int i = j * 512 + tid;
      uint4 ku = *(const uint4*)(kg + (size_t)i * 8);
      int row = i >> 2, c = i & 3;
      int swk = (row >> 1) & 7;
      *(uint2*)(Ks + row * 32 + (((2 * c)     ^ swk) << 2)) = make_uint2(ku.x, ku.y);
      *(uint2*)(Ks + row * 32 + (((2 * c + 1) ^ swk) << 2)) = make_uint2(ku.z, ku.w);
      uint4 vu = *(const uint4*)(vg + (size_t)i * 8);
      int vr2 = i >> 6, vc = i & 63;
      int swv = vr2 & 15;
      *(uint2*)(Vs + vr2 * 512 + (((2 * vc)     ^ swv) << 2)) = make_uint2(vu.x, vu.y);
      *(uint2*)(Vs + vr2 * 512 + (((2 * vc + 1) ^ swv) << 2)) = make_uint2(vu.z, vu.w);
    }
  }
  // Q B-frags (x32), pre-scaled by log2(e)/sqrt(32).
  uint4 qf8[4];
  {
    const u16* qbase = wq_att + (tbase + q0) * 128 + h * 32;
    const __half2 sc2 = __floats2half2_rn(0.25500527f, 0.25500527f);
#pragma unroll
    for (int nt = 0; nt < 4; nt++) {
      const u16* qr = qbase + (size_t)(nt * 16 + l15) * 128 + l4 * 4;
      uint2 u0 = *(const uint2*)(qr);
      uint2 u1 = *(const uint2*)(qr + 16);
      u32 w0 = __builtin_bit_cast(u32, __hmul2(__builtin_bit_cast(__half2, u0.x), sc2));
      u32 w1 = __builtin_bit_cast(u32, __hmul2(__builtin_bit_cast(__half2, u0.y), sc2));
      u32 w2 = __builtin_bit_cast(u32, __hmul2(__builtin_bit_cast(__half2, u1.x), sc2));
      u32 w3 = __builtin_bit_cast(u32, __hmul2(__builtin_bit_cast(__half2, u1.y), sc2));
      qf8[nt] = make_uint4(w0, w1, w2, w3);
    }
  }
  f32x4 O[2][4];
  f32x4 LS[4];
#pragma unroll
  for (int a = 0; a < 4; a++) {
    O[0][a] = (f32x4){0.f, 0.f, 0.f, 0.f};
    O[1][a] = (f32x4){0.f, 0.f, 0.f, 0.f};
    LS[a] = (f32x4){0.f, 0.f, 0.f, 0.f};
  }
  const f16x8 ones8 = {(_Float16)1.f, (_Float16)1.f, (_Float16)1.f, (_Float16)1.f,
                       (_Float16)1.f, (_Float16)1.f, (_Float16)1.f, (_Float16)1.f};
  __syncthreads();   // the only barrier

  for (int t0 = 0; t0 < 512; t0 += 64) {
#pragma unroll
    for (int mp = 0; mp < 2; mp++) {
      int krA = t0 + mp * 32 + l15;
      int krB = krA + 16;
      const u16* kpA = Ks + krA * 32;
      const u16* kpB = Ks + krB * 32;
      int swkA = (krA >> 1) & 7;
      int swkB = (krB >> 1) & 7;
      uint2 a0A = *(const uint2*)(kpA + ((l4       ^ swkA) << 2));
      uint2 a1A = *(const uint2*)(kpA + (((4 + l4) ^ swkA) << 2));
      uint2 a0B = *(const uint2*)(kpB + ((l4       ^ swkB) << 2));
      uint2 a1B = *(const uint2*)(kpB + (((4 + l4) ^ swkB) << 2));
      f16x8 a8A = cat8(a0A, a1A);
      f16x8 a8B = cat8(a0B, a1B);
      int gA = (t0 >> 2) + mp * 8 + l4;
      int gB = gA + 4;
      uint2 vA0 = *(const uint2*)(Vs + l15 * 512        + ((gA ^ l15) << 2));
      uint2 vB0 = *(const uint2*)(Vs + l15 * 512        + ((gB ^ l15) << 2));
      uint2 vA1 = *(const uint2*)(Vs + (16 + l15) * 512 + ((gA ^ l15) << 2));
      uint2 vB1 = *(const uint2*)(Vs + (16 + l15) * 512 + ((gB ^ l15) << 2));
      f16x8 v80 = cat8(vA0, vB0);
      f16x8 v81 = cat8(vA1, vB1);
      __builtin_amdgcn_s_setprio(1);
#pragma unroll
      for (int nt = 0; nt < 4; nt++) {
        f16x8 qb = __builtin_bit_cast(f16x8, qf8[nt]);
        f32x4 z = {0.f, 0.f, 0.f, 0.f};
        f32x4 sA = mfma32(a8A, qb, z);
        f32x4 sB = mfma32(a8B, qb, z);
        float e0 = __builtin_amdgcn_exp2f(sA[0]);
        float e1 = __builtin_amdgcn_exp2f(sA[1]);
        float e2 = __builtin_amdgcn_exp2f(sA[2]);
        float e3 = __builtin_amdgcn_exp2f(sA[3]);
        float e4 = __builtin_amdgcn_exp2f(sB[0]);
        float e5 = __builtin_amdgcn_exp2f(sB[1]);
        float e6 = __builtin_amdgcn_exp2f(sB[2]);
        float e7 = __builtin_amdgcn_exp2f(sB[3]);
        uint4 pu = make_uint4(
            __builtin_bit_cast(u32, __builtin_amdgcn_cvt_pkrtz(e0, e1)),
            __builtin_bit_cast(u32, __builtin_amdgcn_cvt_pkrtz(e2, e3)),
            __builtin_bit_cast(u32, __builtin_amdgcn_cvt_pkrtz(e4, e5)),
            __builtin_bit_cast(u32, __builtin_amdgcn_cvt_pkrtz(e6, e7)));
        f16x8 pb = __builtin_bit_cast(f16x8, pu);
        LS[nt]   = mfma32(ones8, pb, LS[nt]);
        O[0][nt] = mfma32(v80, pb, O[0][nt]);
        O[1][nt] = mfma32(v81, pb, O[1][nt]);
      }
      __builtin_amdgcn_s_setprio(0);
    }
  }
  // store att (overwrites this block's own q-rows / h-col slice only)
#pragma unroll
  for (int nt = 0; nt < 4; nt++) {
    float r = 1.f / LS[nt][0];
#pragma unroll
    for (int mt2 = 0; mt2 < 2; mt2++) {
      uint2 ov = make_uint2(pack2h(O[mt2][nt][0] * r, O[mt2][nt][1] * r),
                            pack2h(O[mt2][nt][2] * r, O[mt2][nt][3] * r));
      *(uint2*)(wq_att + (tbase + q0 + nt * 16 + l15) * 128 + h * 32 + mt2 * 16 + l4 * 4) = ov;
    }
  }
}

// ---------------------------------------------------------------------------
// Output projection, SWAPPED operands: D'[n][t], lane holds 4 consecutive n
// for one token -> dense uint2 stores of (att @ Wo^T + bo) into po[T][128].
// No mask, no atomics: masked slots are simply never gathered by ln_k.
__global__ __launch_bounds__(256) void proj_k(
    const u16* __restrict__ watt, const u16* __restrict__ bp, const float* __restrict__ bo,
    u16* __restrict__ po) {
  __shared__ uint4 As[64 * 16];
  int tid = threadIdx.x;
  int t0 = blockIdx.x * 64;
  {
    int r = tid >> 2, qd = tid & 3;
    const uint4* src = (const uint4*)(watt + (size_t)(t0 + r) * D_ + qd * 32);
#pragma unroll
    for (int c = 0; c < 4; c++) {
      int byteoff = (qd * 64 + c * 16) ^ ((r & 7) << 4);
      As[r * 16 + (byteoff >> 4)] = src[c];
    }
  }
  __syncthreads();
  int lane = tid & 63, wid = tid >> 6;
  int l15 = lane & 15, l4 = lane >> 4;
  int wm = wid & 1, wn = wid >> 1;
  uint2 bfrag[4][8];
  const uint2* bpp = (const uint2*)bp;
#pragma unroll
  for (int nt = 0; nt < 4; nt++) {
    int ntg = wn * 4 + nt;
#pragma unroll
    for (int ks = 0; ks < 8; ks++)
      bfrag[nt][ks] = bpp[(3 * 64 + ntg * 8 + ks) * 64 + lane];
  }
  uint2 afr[2][8];
#pragma unroll
  for (int tt = 0; tt < 2; tt++) {
    int row = wm * 32 + tt * 16 + l15;
#pragma unroll
    for (int ks = 0; ks < 8; ks++) {
      int byteoff = (ks * 32 + (l4 << 3)) ^ ((row & 7) << 4);
      afr[tt][ks] = *(const uint2*)((const char*)As + row * 256 + byteoff);
    }
  }
  // acc[nt][tt]: D'[n][t], n = wn*64+nt*16+4*l4+i, t = wm*32+tt*16+l15
  f32x4 acc[4][2];
#pragma unroll
  for (int nt = 0; nt < 4; nt++) {
    float4 bo4 = *(const float4*)(bo + wn * 64 + nt * 16 + l4 * 4);
    f32x4 bz = {bo4.x, bo4.y, bo4.z, bo4.w};
    acc[nt][0] = bz;
    acc[nt][1] = bz;
  }
#pragma unroll
  for (int kp = 0; kp < 4; kp++) {
#pragma unroll
    for (int nt = 0; nt < 4; nt++) {
      f16x8 a = cat8(bfrag[nt][2 * kp], bfrag[nt][2 * kp + 1]);
#pragma unroll
      for (int tt = 0; tt < 2; tt++) {
        f16x8 b = cat8(afr[tt][2 * kp], afr[tt][2 * kp + 1]);
        acc[nt][tt] = mfma32(a, b, acc[nt][tt]);
      }
    }
  }
#pragma unroll
  for (int tt = 0; tt < 2; tt++) {
    size_t tok = t0 + wm * 32 + tt * 16 + l15;
#pragma unroll
    for (int nt = 0; nt < 4; nt++) {
      int n0 = wn * 64 + nt * 16 + l4 * 4;
      f32x4 a = acc[nt][tt];
      uint2 pv = make_uint2(pack2h(a[0], a[1]), pack2h(a[2], a[3]));
      *(uint2*)(po + tok * D_ + n0) = pv;
    }
  }
}

// ---------------------------------------------------------------------------
// Gather-aggregate + residual + LayerNorm. Per (b,n) row: sum deg=cnt[n]
// po rows (fp32 accum), h = x + sum/max(cnt,1), LN over D.
__global__ __launch_bounds__(256) void ln_k(
    const float* __restrict__ x, const float* __restrict__ cnt,
    const u16* __restrict__ po, const int* __restrict__ slots,
    const float* __restrict__ g, const float* __restrict__ bta, float* __restrict__ out) {
  int tid = threadIdx.x;
  int row = blockIdx.x * 8 + (tid >> 5);
  if (row >= B_ * N_) return;
  int l32 = tid & 31;
  int n = row % N_;
  int b = row / N_;
  float c = cnt[n];
  int deg = (int)c;
  if (deg > CAP_) deg = CAP_;
  float rc = 1.f / (c > 1.f ? c : 1.f);
  float4 a = make_float4(0.f, 0.f, 0.f, 0.f);
  const int* sl = slots + n * CAP_;
  for (int j = 0; j < deg; j++) {
    int s = sl[j];
    uint2 u = *(const uint2*)(po + ((size_t)b * PS_ + s) * D_ + l32 * 4);
    float2 a01 = __half22float2(__builtin_bit_cast(__half2, u.x));
    float2 a23 = __half22float2(__builtin_bit_cast(__half2, u.y));
    a.x += a01.x; a.y += a01.y; a.z += a23.x; a.w += a23.y;
  }
  size_t off = (size_t)row * D_ + l32 * 4;
  float4 xa = *(const float4*)(x + off);
  float4 hv = make_float4(fmaf(a.x, rc, xa.x), fmaf(a.y, rc, xa.y),
                          fmaf(a.z, rc, xa.z), fmaf(a.w, rc, xa.w));
  float s = hv.x + hv.y + hv.z + hv.w;
  float s2 = hv.x * hv.x + hv.y * hv.y + hv.z * hv.z + hv.w * hv.w;
#pragma unroll
  for (int m = 16; m >= 1; m >>= 1) {
    s += __shfl_xor(s, m);
    s2 += __shfl_xor(s2, m);
  }
  float mu = s * 0.0078125f;
  float var = s2 * 0.0078125f - mu * mu;
  float rstd = rsqrtf(var + 1e-5f);
  float4 gv = *(const float4*)(g + l32 * 4);
  float4 bv = *(const float4*)(bta + l32 * 4);
  float4 ov = make_float4((hv.x - mu) * rstd * gv.x + bv.x,
                          (hv.y - mu) * rstd * gv.y + bv.y,
                          (hv.z - mu) * rstd * gv.z + bv.z,
                          (hv.w - mu) * rstd * gv.w + bv.w);
  *(float4*)(out + off) = ov;
}

// ---------------------------------------------------------------------------
extern "C" void kernel_launch(void* const* d_in, const int* in_sizes, int n_in,
                              void* d_out, int out_size, void* d_ws, size_t ws_size,
                              hipStream_t stream) {
  const float* x   = (const float*)d_in[0];
  const float* Wq  = (const float*)d_in[1];
  const float* bq  = (const float*)d_in[2];
  const float* Wk  = (const float*)d_in[3];
  const float* bk  = (const float*)d_in[4];
  const float* Wv  = (const float*)d_in[5];
  const float* bv  = (const float*)d_in[6];
  const float* Wo  = (const float*)d_in[7];
  const float* bo  = (const float*)d_in[8];
  const float* lng = (const float*)d_in[9];
  const float* lnb = (const float*)d_in[10];
  const int* pidx  = (const int*)d_in[11];
  const void* cmask = d_in[12];
  float* out = (float*)d_out;
  char* ws = (char*)d_ws;

  u16* wsq = (u16*)(ws + OFF_Q);
  u16* wsk = (u16*)(ws + OFF_K);
  u16* wsvt = (u16*)(ws + OFF_V);
  u16* wbp = (u16*)(ws + OFF_BP);
  float* wcnt = (float*)(ws + OFF_CNT);
  float* wcm  = (float*)(ws + OFF_CM);
  int* wflag  = (int*)(ws + OFF_FLAG);
  // after attn: K region -> po[T][128] fp16; V region -> cursor[N] + slots[N*CAP]
  u16* po = (u16*)(ws + OFF_K);
  int* cursor = (int*)(ws + OFF_V);
  int* slots = (int*)(ws + OFF_V + CUR_BYTES);

  hipMemsetAsync(ws + OFF_CNT, 0, (OFF_FLAG + 4) - OFF_CNT, stream);

  probe_mask_k<<<200, 256, 0, stream>>>((const unsigned char*)cmask, wflag);
  mask_cnt_k<<<200, 256, 0, stream>>>(cmask, pidx, wflag, wcm, wcnt);
  pack_w_k<<<64, 256, 0, stream>>>(Wq, Wk, Wv, Wo, wbp);
  qkv_k<<<1600, 256, 0, stream>>>(x, pidx, wbp, bq, bk, bv, wsq);
  attn_k<<<800, 512, 0, stream>>>(wsq, wsk, wsvt);
  // V region dead: build inverted index there
  hipMemsetAsync(cursor, 0, CUR_BYTES, stream);
  fill_k<<<200, 256, 0, stream>>>(cmask, pidx, wflag, cursor, slots);
  proj_k<<<1600, 256, 0, stream>>>(wsq, wbp, bo, po);
  ln_k<<<10241, 256, 0, stream>>>(x, wcnt, po, slots, lng, lnb, out);
}

// Round 12
// 156.972 us; speedup vs baseline: 3.3462x; 1.0414x over previous
//
#include <hip/hip_runtime.h>
#include <hip/hip_bf16.h>
#include <hip/hip_fp16.h>

// Problem constants
#define B_ 2
#define N_ 40962
#define D_ 128
#define H_ 4
#define P_ 100
#define S_ 512
#define T_ 102400      // B*P*S tokens
#define PS_ 51200      // P*S
#define CAP_ 32        // inverted-index capacity per node

typedef unsigned short u16;
typedef unsigned int u32;
typedef _Float16 f16x4 __attribute__((ext_vector_type(4)));
typedef _Float16 f16x8 __attribute__((ext_vector_type(8)));
typedef float f32x4 __attribute__((ext_vector_type(4)));

// Workspace byte offsets (total ~79.2 MB)
#define OFF_Q    0ull           // q fp16 [T][128]  (later reused as att)
#define OFF_K    26214400ull    // k fp16 per-head [bp*4+h][512][32]; reused as po[T][128] fp16 after attn
#define OFF_V    52428800ull    // v fp16 V^T [bp*4+h][32][512]; reused as cursor[N]+slots[N*32] after attn
#define OFF_BP   78643200ull    // packed W frags: 4 mats x 4096 lane-frags x 8B
#define OFF_FLAG 79142920ull    // int dtype flag for core_mask
#define CUR_BYTES ((size_t)N_ * 4)

__device__ __forceinline__ u32 pack2h(float a, float b) {
  __half2 h = __floats2half2_rn(a, b);
  return __builtin_bit_cast(u32, h);
}
__device__ __forceinline__ f16x8 cat8(uint2 lo, uint2 hi) {
  return __builtin_bit_cast(f16x8, make_uint4(lo.x, lo.y, hi.x, hi.y));
}

// 16x16x32 f16 MFMA; x32 frag = concat of two x16 half-frags (k 0..15, 16..31).
__device__ __forceinline__ f32x4 mfma32(f16x8 a, f16x8 b, f32x4 c) {
#if __has_builtin(__builtin_amdgcn_mfma_f32_16x16x32_f16)
  return __builtin_amdgcn_mfma_f32_16x16x32_f16(a, b, c, 0, 0, 0);
#else
  f16x4 alo = {a[0], a[1], a[2], a[3]}, ahi = {a[4], a[5], a[6], a[7]};
  f16x4 blo = {b[0], b[1], b[2], b[3]}, bhi = {b[4], b[5], b[6], b[7]};
  c = __builtin_amdgcn_mfma_f32_16x16x16f16(alo, blo, c, 0, 0, 0);
  return __builtin_amdgcn_mfma_f32_16x16x16f16(ahi, bhi, c, 0, 0, 0);
#endif
}

__device__ __forceinline__ bool mask_on(const void* mask, int fl, int i) {
  if (fl & 1) return ((const unsigned char*)mask)[i] != 0;
  if (fl & 2) return ((const float*)mask)[i] != 0.f;
  return ((const int*)mask)[i] != 0;
}

// ---------------------------------------------------------------------------
// Probe core_mask storage format (bool8 / int32 / float32); wave-reduced OR.
__global__ void probe_mask_k(const unsigned char* __restrict__ mb, int* __restrict__ flag) {
  int i = blockIdx.x * 256 + threadIdx.x;
  int f = 0;
  unsigned char v = mb[i];
  if (v) {
    int m4 = i & 3;
    if (m4 == 1) f |= 1;
    else if (m4 == 3) f |= 2;
  }
#pragma unroll
  for (int m = 32; m >= 1; m >>= 1) f |= __shfl_xor(f, m);
  if ((threadIdx.x & 63) == 0 && f) atomicOr(flag, f);
}

// Build inverted index: for each masked slot ps, append to its node's list.
// cursor[n] doubles as the count (cnt) consumed by ln_k.
__global__ void fill_k(const void* __restrict__ mask, const int* __restrict__ pidx,
                       const int* __restrict__ flag, int* __restrict__ cursor,
                       int* __restrict__ slots) {
  int i = blockIdx.x * 256 + threadIdx.x;
  int fl = *flag;
  if (mask_on(mask, fl, i)) {
    int n = pidx[i];
    int pos = atomicAdd(&cursor[n], 1);
    if (pos < CAP_) slots[n * CAP_ + pos] = i;
  }
}

// ---------------------------------------------------------------------------
// Pack Wq/Wk/Wv/Wo into MFMA fragment order (fp16). Same bytes serve as
// B-operand (l15->n, 4*l4+i->k) and A-operand (l15->row n, 4*l4+i->k).
__global__ void pack_w_k(const float* __restrict__ Wq, const float* __restrict__ Wk,
                         const float* __restrict__ Wv, const float* __restrict__ Wo,
                         u16* __restrict__ bp) {
  int gi = blockIdx.x * 256 + threadIdx.x;   // < 16384
  int m = gi >> 12;
  int r = gi & 4095;
  int fi = r >> 6;         // nt*8 + ks
  int l = r & 63;
  int nt = fi >> 3, ks = fi & 7;
  const float* W = (m == 0) ? Wq : (m == 1) ? Wk : (m == 2) ? Wv : Wo;
  int n = nt * 16 + (l & 15);
  int k0 = ks * 16 + ((l >> 4) << 2);
  float4 w = *(const float4*)(W + n * 128 + k0);
  *(uint2*)(bp + (size_t)gi * 4) = make_uint2(pack2h(w.x, w.y), pack2h(w.z, w.w));
}

// ---------------------------------------------------------------------------
// Round-6 qkv (proven 56 us): gather 64 rows once via LDS + all three
// projections. mat 0 -> q [T][128]; mat 1 -> K per-head [bp*4+h][512][32];
// mat 2 -> V^T [bp*4+h][32][512].
__global__ __launch_bounds__(256) void qkv_k(
    const float* __restrict__ x, const int* __restrict__ pidx,
    const u16* __restrict__ bp,
    const float* __restrict__ bq, const float* __restrict__ bk, const float* __restrict__ bv,
    u16* __restrict__ qkv) {
  __shared__ uint4 As[64 * 16];   // 64 rows x 128 fp16, XOR-swizzled
  int tid = threadIdx.x;
  int t0 = blockIdx.x * 64;
  {
    int r = tid >> 2, qd = tid & 3;
    int T = t0 + r;
    int b = T / PS_;
    int ps = T - b * PS_;
    int pi = pidx[ps];
    const float4* src = (const float4*)(x + ((size_t)b * N_ + pi) * D_ + qd * 32);
    u32 us[16];
#pragma unroll
    for (int j = 0; j < 8; j++) {
      float4 f = src[j];
      us[2 * j]     = pack2h(f.x, f.y);
      us[2 * j + 1] = pack2h(f.z, f.w);
    }
#pragma unroll
    for (int c = 0; c < 4; c++) {
      int byteoff = (qd * 64 + c * 16) ^ ((r & 7) << 4);
      As[r * 16 + (byteoff >> 4)] = make_uint4(us[4 * c], us[4 * c + 1], us[4 * c + 2], us[4 * c + 3]);
    }
  }
  __syncthreads();
  int lane = tid & 63, wid = tid >> 6;
  int l15 = lane & 15, l4 = lane >> 4;
  int wm = wid & 1, wn = wid >> 1;
  uint2 afr[2][8];
#pragma unroll
  for (int mt = 0; mt < 2; mt++) {
    int row = wm * 32 + mt * 16 + l15;
#pragma unroll
    for (int ks = 0; ks < 8; ks++) {
      int byteoff = (ks * 32 + (l4 << 3)) ^ ((row & 7) << 4);
      afr[mt][ks] = *(const uint2*)((const char*)As + row * 256 + byteoff);
    }
  }
  const uint2* bpp = (const uint2*)bp;
#pragma unroll 1
  for (int mat = 0; mat < 3; mat++) {
    uint2 bfrag[4][8];
#pragma unroll
    for (int nt = 0; nt < 4; nt++) {
      int ntg = wn * 4 + nt;
#pragma unroll
      for (int ks = 0; ks < 8; ks++)
        bfrag[nt][ks] = bpp[(mat * 64 + ntg * 8 + ks) * 64 + lane];
    }
    const float* bias = (mat == 0) ? bq : (mat == 1) ? bk : bv;
    f32x4 acc[2][4];
#pragma unroll
    for (int nt = 0; nt < 4; nt++) {
      float bvv = bias[wn * 64 + nt * 16 + l15];
#pragma unroll
      for (int mt = 0; mt < 2; mt++) {
        f32x4 z = {bvv, bvv, bvv, bvv};
        acc[mt][nt] = z;
      }
    }
#pragma unroll
    for (int kp = 0; kp < 4; kp++) {
#pragma unroll
      for (int mt = 0; mt < 2; mt++) {
        f16x8 a = cat8(afr[mt][2 * kp], afr[mt][2 * kp + 1]);
#pragma unroll
        for (int nt = 0; nt < 4; nt++) {
          f16x8 b = cat8(bfrag[nt][2 * kp], bfrag[nt][2 * kp + 1]);
          acc[mt][nt] = mfma32(a, b, acc[mt][nt]);
        }
      }
    }
    if (mat == 2) {
      u16* vt = qkv + (size_t)2 * T_ * D_;
#pragma unroll
      for (int mt = 0; mt < 2; mt++) {
        int rbase = t0 + wm * 32 + mt * 16 + (l4 << 2);
        int bpi = rbase >> 9;        // b*P + p (same for all 4 i)
        int s = rbase & 511;
#pragma unroll
        for (int nt = 0; nt < 4; nt++) {
          int col = wn * 64 + nt * 16 + l15;
          uint2 pv = make_uint2(pack2h(acc[mt][nt][0], acc[mt][nt][1]),
                                pack2h(acc[mt][nt][2], acc[mt][nt][3]));
          *(uint2*)(vt + ((size_t)(bpi * 4 + (col >> 5)) * 32 + (col & 31)) * 512 + s) = pv;
        }
      }
    } else if (mat == 1) {
      u16* kh = qkv + (size_t)T_ * D_;
#pragma unroll
      for (int mt = 0; mt < 2; mt++) {
        int rbase = t0 + wm * 32 + mt * 16 + (l4 << 2);
        int bpi = rbase >> 9;
        int s = rbase & 511;
#pragma unroll
        for (int nt = 0; nt < 4; nt++) {
          int col = wn * 64 + nt * 16 + l15;
          int hd = col & 31, ch = col >> 5;
#pragma unroll
          for (int i = 0; i < 4; i++) {
            __half hv = __float2half(acc[mt][nt][i]);
            kh[((size_t)(bpi * 4 + ch) * 512 + (s + i)) * 32 + hd] = __builtin_bit_cast(u16, hv);
          }
        }
      }
    } else {
      u16* outp = qkv;
#pragma unroll
      for (int mt = 0; mt < 2; mt++) {
        int rbase = t0 + wm * 32 + mt * 16 + (l4 << 2);
#pragma unroll
        for (int nt = 0; nt < 4; nt++) {
          int col = wn * 64 + nt * 16 + l15;
#pragma unroll
          for (int i = 0; i < 4; i++) {
            __half hv = __float2half(acc[mt][nt][i]);
            outp[(size_t)(rbase + i) * D_ + col] = __builtin_bit_cast(u16, hv);
          }
        }
      }
    }
  }
}

// ---------------------------------------------------------------------------
// MFMA flash-attention, swapped operands, x32 MFMA. One block = (bp, h),
// 512 threads / 8 waves. V^T staged in LDS (32 KB -> up to 4 blocks/CU);
// K x32 A-frags read directly from L2-resident global (correctness verified
// round 10). launch_bounds (512,4): VGPR budget 128 -> no spill (~60 live).
__global__ __launch_bounds__(512, 4) void attn_k(
    u16* wq_att, const u16* __restrict__ wk, const u16* __restrict__ wvt) {
  __shared__ __align__(16) u16 Vs[32 * 512];  // [hd][512 k], 8B-granule swizzle
  int tid = threadIdx.x;
  int bid = blockIdx.x;
  int h = bid & 3;
  int bp = bid >> 2;
  int lane = tid & 63, w = tid >> 6;
  int l15 = lane & 15, l4 = lane >> 4;
  size_t tbase = (size_t)bp * 512;
  int q0 = w * 64;
  const u16* kg = wk + (size_t)(bp * 4 + h) * 512 * 32;
  // stage V^T (contiguous 32 KB)
  {
    const u16* vg = wvt + (size_t)(bp * 4 + h) * 32 * 512;
#pragma unroll
    for (int j = 0; j < 4; j++) {
      int i = j * 512 + tid;
      uint4 vu = *(const uint4*)(vg + (size_t)i * 8);
      int vr2 = i >> 6, vc = i & 63;
      int swv = vr2 & 15;
      *(uint2*)(Vs + vr2 * 512 + (((2 * vc)     ^ swv) << 2)) = make_uint2(vu.x, vu.y);
      *(uint2*)(Vs + vr2 * 512 + (((2 * vc + 1) ^ swv) << 2)) = make_uint2(vu.z, vu.w);
    }
  }
  // Q B-frags (x32), pre-scaled by log2(e)/sqrt(32).
  uint4 qf8[4];
  {
    const u16* qbase = wq_att + (tbase + q0) * 128 + h * 32;
    const __half2 sc2 = __floats2half2_rn(0.25500527f, 0.25500527f);
#pragma unroll
    for (int nt = 0; nt < 4; nt++) {
      const u16* qr = qbase + (size_t)(nt * 16 + l15) * 128 + l4 * 4;
      uint2 u0 = *(const uint2*)(qr);
      uint2 u1 = *(const uint2*)(qr + 16);
      u32 w0 = __builtin_bit_cast(u32, __hmul2(__builtin_bit_cast(__half2, u0.x), sc2));
      u32 w1 = __builtin_bit_cast(u32, __hmul2(__builtin_bit_cast(__half2, u0.y), sc2));
      u32 w2 = __builtin_bit_cast(u32, __hmul2(__builtin_bit_cast(__half2, u1.x), sc2));
      u32 w3 = __builtin_bit_cast(u32, __hmul2(__builtin_bit_cast(__half2, u1.y), sc2));
      qf8[nt] = make_uint4(w0, w1, w2, w3);
    }
  }
  f32x4 O[2][4];
  f32x4 LS[4];
#pragma unroll
  for (int a = 0; a < 4; a++) {
    O[0][a] = (f32x4){0.f, 0.f, 0.f, 0.f};
    O[1][a] = (f32x4){0.f, 0.f, 0.f, 0.f};
    LS[a] = (f32x4){0.f, 0.f, 0.f, 0.f};
  }
  const f16x8 ones8 = {(_Float16)1.f, (_Float16)1.f, (_Float16)1.f, (_Float16)1.f,
                       (_Float16)1.f, (_Float16)1.f, (_Float16)1.f, (_Float16)1.f};
  __syncthreads();   // the only barrier (V staging)

  for (int t0 = 0; t0 < 512; t0 += 64) {
#pragma unroll
    for (int mp = 0; mp < 2; mp++) {
      // K x32 A-frags straight from global (L2-hot)
      const u16* kpA = kg + (size_t)(t0 + mp * 32 + l15) * 32;
      const u16* kpB = kpA + 16 * 32;
      uint2 a0A = *(const uint2*)(kpA + l4 * 4);
      uint2 a1A = *(const uint2*)(kpA + 16 + l4 * 4);
      uint2 a0B = *(const uint2*)(kpB + l4 * 4);
      uint2 a1B = *(const uint2*)(kpB + 16 + l4 * 4);
      f16x8 a8A = cat8(a0A, a1A);
      f16x8 a8B = cat8(a0B, a1B);
      int gA = (t0 >> 2) + mp * 8 + l4;
      int gB = gA + 4;
      uint2 vA0 = *(const uint2*)(Vs + l15 * 512        + ((gA ^ l15) << 2));
      uint2 vB0 = *(const uint2*)(Vs + l15 * 512        + ((gB ^ l15) << 2));
      uint2 vA1 = *(const uint2*)(Vs + (16 + l15) * 512 + ((gA ^ l15) << 2));
      uint2 vB1 = *(const uint2*)(Vs + (16 + l15) * 512 + ((gB ^ l15) << 2));
      f16x8 v80 = cat8(vA0, vB0);
      f16x8 v81 = cat8(vA1, vB1);
      __builtin_amdgcn_s_setprio(1);
#pragma unroll
      for (int nt = 0; nt < 4; nt++) {
        f16x8 qb = __builtin_bit_cast(f16x8, qf8[nt]);
        f32x4 z = {0.f, 0.f, 0.f, 0.f};
        f32x4 sA = mfma32(a8A, qb, z);
        f32x4 sB = mfma32(a8B, qb, z);
        float e0 = __builtin_amdgcn_exp2f(sA[0]);
        float e1 = __builtin_amdgcn_exp2f(sA[1]);
        float e2 = __builtin_amdgcn_exp2f(sA[2]);
        float e3 = __builtin_amdgcn_exp2f(sA[3]);
        float e4 = __builtin_amdgcn_exp2f(sB[0]);
        float e5 = __builtin_amdgcn_exp2f(sB[1]);
        float e6 = __builtin_amdgcn_exp2f(sB[2]);
        float e7 = __builtin_amdgcn_exp2f(sB[3]);
        uint4 pu = make_uint4(
            __builtin_bit_cast(u32, __builtin_amdgcn_cvt_pkrtz(e0, e1)),
            __builtin_bit_cast(u32, __builtin_amdgcn_cvt_pkrtz(e2, e3)),
            __builtin_bit_cast(u32, __builtin_amdgcn_cvt_pkrtz(e4, e5)),
            __builtin_bit_cast(u32, __builtin_amdgcn_cvt_pkrtz(e6, e7)));
        f16x8 pb = __builtin_bit_cast(f16x8, pu);
        LS[nt]   = mfma32(ones8, pb, LS[nt]);
        O[0][nt] = mfma32(v80, pb, O[0][nt]);
        O[1][nt] = mfma32(v81, pb, O[1][nt]);
      }
      __builtin_amdgcn_s_setprio(0);
    }
  }
  // store att (overwrites this block's own q-rows / h-col slice only)
#pragma unroll
  for (int nt = 0; nt < 4; nt++) {
    float r = 1.f / LS[nt][0];
#pragma unroll
    for (int mt2 = 0; mt2 < 2; mt2++) {
      uint2 ov = make_uint2(pack2h(O[mt2][nt][0] * r, O[mt2][nt][1] * r),
                            pack2h(O[mt2][nt][2] * r, O[mt2][nt][3] * r));
      *(uint2*)(wq_att + (tbase + q0 + nt * 16 + l15) * 128 + h * 32 + mt2 * 16 + l4 * 4) = ov;
    }
  }
}

// ---------------------------------------------------------------------------
// Output projection, SWAPPED operands: D'[n][t], lane holds 4 consecutive n
// for one token -> dense uint2 stores of (att @ Wo^T + bo) into po[T][128].
// No mask, no atomics: masked slots are simply never gathered by ln_k.
__global__ __launch_bounds__(256) void proj_k(
    const u16* __restrict__ watt, const u16* __restrict__ bp, const float* __restrict__ bo,
    u16* __restrict__ po) {
  __shared__ uint4 As[64 * 16];
  int tid = threadIdx.x;
  int t0 = blockIdx.x * 64;
  {
    int r = tid >> 2, qd = tid & 3;
    const uint4* src = (const uint4*)(watt + (size_t)(t0 + r) * D_ + qd * 32);
#pragma unroll
    for (int c = 0; c < 4; c++) {
      int byteoff = (qd * 64 + c * 16) ^ ((r & 7) << 4);
      As[r * 16 + (byteoff >> 4)] = src[c];
    }
  }
  __syncthreads();
  int lane = tid & 63, wid = tid >> 6;
  int l15 = lane & 15, l4 = lane >> 4;
  int wm = wid & 1, wn = wid >> 1;
  uint2 bfrag[4][8];
  const uint2* bpp = (const uint2*)bp;
#pragma unroll
  for (int nt = 0; nt < 4; nt++) {
    int ntg = wn * 4 + nt;
#pragma unroll
    for (int ks = 0; ks < 8; ks++)
      bfrag[nt][ks] = bpp[(3 * 64 + ntg * 8 + ks) * 64 + lane];
  }
  uint2 afr[2][8];
#pragma unroll
  for (int tt = 0; tt < 2; tt++) {
    int row = wm * 32 + tt * 16 + l15;
#pragma unroll
    for (int ks = 0; ks < 8; ks++) {
      int byteoff = (ks * 32 + (l4 << 3)) ^ ((row & 7) << 4);
      afr[tt][ks] = *(const uint2*)((const char*)As + row * 256 + byteoff);
    }
  }
  // acc[nt][tt]: D'[n][t], n = wn*64+nt*16+4*l4+i, t = wm*32+tt*16+l15
  f32x4 acc[4][2];
#pragma unroll
  for (int nt = 0; nt < 4; nt++) {
    float4 bo4 = *(const float4*)(bo + wn * 64 + nt * 16 + l4 * 4);
    f32x4 bz = {bo4.x, bo4.y, bo4.z, bo4.w};
    acc[nt][0] = bz;
    acc[nt][1] = bz;
  }
#pragma unroll
  for (int kp = 0; kp < 4; kp++) {
#pragma unroll
    for (int nt = 0; nt < 4; nt++) {
      f16x8 a = cat8(bfrag[nt][2 * kp], bfrag[nt][2 * kp + 1]);
#pragma unroll
      for (int tt = 0; tt < 2; tt++) {
        f16x8 b = cat8(afr[tt][2 * kp], afr[tt][2 * kp + 1]);
        acc[nt][tt] = mfma32(a, b, acc[nt][tt]);
      }
    }
  }
#pragma unroll
  for (int tt = 0; tt < 2; tt++) {
    size_t tok = t0 + wm * 32 + tt * 16 + l15;
#pragma unroll
    for (int nt = 0; nt < 4; nt++) {
      int n0 = wn * 64 + nt * 16 + l4 * 4;
      f32x4 a = acc[nt][tt];
      uint2 pv = make_uint2(pack2h(a[0], a[1]), pack2h(a[2], a[3]));
      *(uint2*)(po + tok * D_ + n0) = pv;
    }
  }
}

// ---------------------------------------------------------------------------
// Gather-aggregate + residual + LayerNorm. Per (b,n) row: sum deg rows of po
// (fp32 accum) via the inverted index, h = x + sum/max(cnt,1), LN over D.
__global__ __launch_bounds__(256) void ln_k(
    const float* __restrict__ x, const int* __restrict__ cursor,
    const u16* __restrict__ po, const int* __restrict__ slots,
    const float* __restrict__ g, const float* __restrict__ bta, float* __restrict__ out) {
  int tid = threadIdx.x;
  int row = blockIdx.x * 8 + (tid >> 5);
  if (row >= B_ * N_) return;
  int l32 = tid & 31;
  int n = row % N_;
  int b = row / N_;
  int cnt = cursor[n];
  int deg = cnt > CAP_ ? CAP_ : cnt;
  float rc = 1.f / (float)(cnt > 1 ? cnt : 1);
  float4 a = make_float4(0.f, 0.f, 0.f, 0.f);
  const int* sl = slots + n * CAP_;
  for (int j = 0; j < deg; j++) {
    int s = sl[j];
    uint2 u = *(const uint2*)(po + ((size_t)b * PS_ + s) * D_ + l32 * 4);
    float2 a01 = __half22float2(__builtin_bit_cast(__half2, u.x));
    float2 a23 = __half22float2(__builtin_bit_cast(__half2, u.y));
    a.x += a01.x; a.y += a01.y; a.z += a23.x; a.w += a23.y;
  }
  size_t off = (size_t)row * D_ + l32 * 4;
  float4 xa = *(const float4*)(x + off);
  float4 hv = make_float4(fmaf(a.x, rc, xa.x), fmaf(a.y, rc, xa.y),
                          fmaf(a.z, rc, xa.z), fmaf(a.w, rc, xa.w));
  float s = hv.x + hv.y + hv.z + hv.w;
  float s2 = hv.x * hv.x + hv.y * hv.y + hv.z * hv.z + hv.w * hv.w;
#pragma unroll
  for (int m = 16; m >= 1; m >>= 1) {
    s += __shfl_xor(s, m);
    s2 += __shfl_xor(s2, m);
  }
  float mu = s * 0.0078125f;
  float var = s2 * 0.0078125f - mu * mu;
  float rstd = rsqrtf(var + 1e-5f);
  float4 gv = *(const float4*)(g + l32 * 4);
  float4 bv = *(const float4*)(bta + l32 * 4);
  float4 ov = make_float4((hv.x - mu) * rstd * gv.x + bv.x,
                          (hv.y - mu) * rstd * gv.y + bv.y,
                          (hv.z - mu) * rstd * gv.z + bv.z,
                          (hv.w - mu) * rstd * gv.w + bv.w);
  *(float4*)(out + off) = ov;
}

// ---------------------------------------------------------------------------
extern "C" void kernel_launch(void* const* d_in, const int* in_sizes, int n_in,
                              void* d_out, int out_size, void* d_ws, size_t ws_size,
                              hipStream_t stream) {
  const float* x   = (const float*)d_in[0];
  const float* Wq  = (const float*)d_in[1];
  const float* bq  = (const float*)d_in[2];
  const float* Wk  = (const float*)d_in[3];
  const float* bk  = (const float*)d_in[4];
  const float* Wv  = (const float*)d_in[5];
  const float* bv  = (const float*)d_in[6];
  const float* Wo  = (const float*)d_in[7];
  const float* bo  = (const float*)d_in[8];
  const float* lng = (const float*)d_in[9];
  const float* lnb = (const float*)d_in[10];
  const int* pidx  = (const int*)d_in[11];
  const void* cmask = d_in[12];
  float* out = (float*)d_out;
  char* ws = (char*)d_ws;

  u16* wsq = (u16*)(ws + OFF_Q);
  u16* wsk = (u16*)(ws + OFF_K);
  u16* wsvt = (u16*)(ws + OFF_V);
  u16* wbp = (u16*)(ws + OFF_BP);
  int* wflag  = (int*)(ws + OFF_FLAG);
  // after attn: K region -> po[T][128] fp16; V region -> cursor[N] + slots[N*CAP]
  u16* po = (u16*)(ws + OFF_K);
  int* cursor = (int*)(ws + OFF_V);
  int* slots = (int*)(ws + OFF_V + CUR_BYTES);

  hipMemsetAsync(wflag, 0, 4, stream);

  probe_mask_k<<<200, 256, 0, stream>>>((const unsigned char*)cmask, wflag);
  pack_w_k<<<64, 256, 0, stream>>>(Wq, Wk, Wv, Wo, wbp);
  qkv_k<<<1600, 256, 0, stream>>>(x, pidx, wbp, bq, bk, bv, wsq);
  attn_k<<<800, 512, 0, stream>>>(wsq, wsk, wsvt);
  // V region dead: build inverted index there (cursor doubles as cnt)
  hipMemsetAsync(cursor, 0, CUR_BYTES, stream);
  fill_k<<<200, 256, 0, stream>>>(cmask, pidx, wflag, cursor, slots);
  proj_k<<<1600, 256, 0, stream>>>(wsq, wbp, bo, po);
  ln_k<<<10241, 256, 0, stream>>>(x, cursor, po, slots, lng, lnb, out);
}

// Round 13
// 154.029 us; speedup vs baseline: 3.4101x; 1.0191x over previous
//
#include <hip/hip_runtime.h>
#include <hip/hip_bf16.h>
#include <hip/hip_fp16.h>

// Problem constants
#define B_ 2
#define N_ 40962
#define D_ 128
#define H_ 4
#define P_ 100
#define S_ 512
#define T_ 102400      // B*P*S tokens
#define PS_ 51200      // P*S
#define CAP_ 32        // inverted-index capacity per node

typedef unsigned short u16;
typedef unsigned int u32;
typedef _Float16 f16x4 __attribute__((ext_vector_type(4)));
typedef _Float16 f16x8 __attribute__((ext_vector_type(8)));
typedef float f32x4 __attribute__((ext_vector_type(4)));

// Workspace byte offsets (total ~79.2 MB)
#define OFF_Q    0ull           // q fp16 [T][128]  (later reused as att)
#define OFF_K    26214400ull    // k fp16 per-head [bp*4+h][512][32]; reused as po[T][128] fp16 after attn
#define OFF_V    52428800ull    // v fp16 V^T [bp*4+h][32][512]; reused as cursor[N]+slots[N*32] after attn
#define OFF_BP   78643200ull    // packed W frags: 4 mats x 4096 lane-frags x 8B
#define OFF_FLAG 79142920ull    // int dtype flag for core_mask
#define CUR_BYTES ((size_t)N_ * 4)

__device__ __forceinline__ u32 pack2h(float a, float b) {
  __half2 h = __floats2half2_rn(a, b);
  return __builtin_bit_cast(u32, h);
}
__device__ __forceinline__ f16x8 cat8(uint2 lo, uint2 hi) {
  return __builtin_bit_cast(f16x8, make_uint4(lo.x, lo.y, hi.x, hi.y));
}

// 16x16x32 f16 MFMA; x32 frag = concat of two x16 half-frags (k 0..15, 16..31).
__device__ __forceinline__ f32x4 mfma32(f16x8 a, f16x8 b, f32x4 c) {
#if __has_builtin(__builtin_amdgcn_mfma_f32_16x16x32_f16)
  return __builtin_amdgcn_mfma_f32_16x16x32_f16(a, b, c, 0, 0, 0);
#else
  f16x4 alo = {a[0], a[1], a[2], a[3]}, ahi = {a[4], a[5], a[6], a[7]};
  f16x4 blo = {b[0], b[1], b[2], b[3]}, bhi = {b[4], b[5], b[6], b[7]};
  c = __builtin_amdgcn_mfma_f32_16x16x16f16(alo, blo, c, 0, 0, 0);
  return __builtin_amdgcn_mfma_f32_16x16x16f16(ahi, bhi, c, 0, 0, 0);
#endif
}

__device__ __forceinline__ bool mask_on(const void* mask, int fl, int i) {
  if (fl & 1) return ((const unsigned char*)mask)[i] != 0;
  if (fl & 2) return ((const float*)mask)[i] != 0.f;
  return ((const int*)mask)[i] != 0;
}

// ---------------------------------------------------------------------------
// Probe core_mask storage format (bool8 / int32 / float32); wave-reduced OR.
__global__ void probe_mask_k(const unsigned char* __restrict__ mb, int* __restrict__ flag) {
  int i = blockIdx.x * 256 + threadIdx.x;
  int f = 0;
  unsigned char v = mb[i];
  if (v) {
    int m4 = i & 3;
    if (m4 == 1) f |= 1;
    else if (m4 == 3) f |= 2;
  }
#pragma unroll
  for (int m = 32; m >= 1; m >>= 1) f |= __shfl_xor(f, m);
  if ((threadIdx.x & 63) == 0 && f) atomicOr(flag, f);
}

// Build inverted index: for each masked slot ps, append to its node's list.
// cursor[n] doubles as the count (cnt) consumed by ln_k.
__global__ void fill_k(const void* __restrict__ mask, const int* __restrict__ pidx,
                       const int* __restrict__ flag, int* __restrict__ cursor,
                       int* __restrict__ slots) {
  int i = blockIdx.x * 256 + threadIdx.x;
  int fl = *flag;
  if (mask_on(mask, fl, i)) {
    int n = pidx[i];
    int pos = atomicAdd(&cursor[n], 1);
    if (pos < CAP_) slots[n * CAP_ + pos] = i;
  }
}

// ---------------------------------------------------------------------------
// Pack Wq/Wk/Wv/Wo into MFMA fragment order (fp16). Same bytes serve as
// B-operand (l15->n, 4*l4+i->k) and A-operand (l15->row n, 4*l4+i->k).
__global__ void pack_w_k(const float* __restrict__ Wq, const float* __restrict__ Wk,
                         const float* __restrict__ Wv, const float* __restrict__ Wo,
                         u16* __restrict__ bp) {
  int gi = blockIdx.x * 256 + threadIdx.x;   // < 16384
  int m = gi >> 12;
  int r = gi & 4095;
  int fi = r >> 6;         // nt*8 + ks
  int l = r & 63;
  int nt = fi >> 3, ks = fi & 7;
  const float* W = (m == 0) ? Wq : (m == 1) ? Wk : (m == 2) ? Wv : Wo;
  int n = nt * 16 + (l & 15);
  int k0 = ks * 16 + ((l >> 4) << 2);
  float4 w = *(const float4*)(W + n * 128 + k0);
  *(uint2*)(bp + (size_t)gi * 4) = make_uint2(pack2h(w.x, w.y), pack2h(w.z, w.w));
}

// ---------------------------------------------------------------------------
// QKV: round-6 staging (64 tokens, 4 waves, 16 KB LDS) + SWAPPED q/k outputs
// (D'[n][t], verified round 7): lane holds 4 consecutive n for one token ->
// all q and per-head-K stores are uint2 (no scalar 2B stores). v original.
// mat 0 -> q [T][128]; mat 1 -> K [bp*4+h][512][32]; mat 2 -> V^T [bp*4+h][32][512].
__global__ __launch_bounds__(256) void qkv_k(
    const float* __restrict__ x, const int* __restrict__ pidx,
    const u16* __restrict__ bp,
    const float* __restrict__ bq, const float* __restrict__ bk, const float* __restrict__ bv,
    u16* __restrict__ qkv) {
  __shared__ uint4 As[64 * 16];   // 64 rows x 128 fp16, XOR-swizzled
  int tid = threadIdx.x;
  int t0 = blockIdx.x * 64;
  {
    int r = tid >> 2, qd = tid & 3;
    int T = t0 + r;
    int b = T / PS_;
    int ps = T - b * PS_;
    int pi = pidx[ps];
    const float4* src = (const float4*)(x + ((size_t)b * N_ + pi) * D_ + qd * 32);
    u32 us[16];
#pragma unroll
    for (int j = 0; j < 8; j++) {
      float4 f = src[j];
      us[2 * j]     = pack2h(f.x, f.y);
      us[2 * j + 1] = pack2h(f.z, f.w);
    }
#pragma unroll
    for (int c = 0; c < 4; c++) {
      int byteoff = (qd * 64 + c * 16) ^ ((r & 7) << 4);
      As[r * 16 + (byteoff >> 4)] = make_uint4(us[4 * c], us[4 * c + 1], us[4 * c + 2], us[4 * c + 3]);
    }
  }
  __syncthreads();
  int lane = tid & 63, wid = tid >> 6;
  int l15 = lane & 15, l4 = lane >> 4;
  int wm = wid & 1, wn = wid >> 1;
  uint2 afr[2][8];
#pragma unroll
  for (int tt = 0; tt < 2; tt++) {
    int row = wm * 32 + tt * 16 + l15;
#pragma unroll
    for (int ks = 0; ks < 8; ks++) {
      int byteoff = (ks * 32 + (l4 << 3)) ^ ((row & 7) << 4);
      afr[tt][ks] = *(const uint2*)((const char*)As + row * 256 + byteoff);
    }
  }
  const uint2* bpp = (const uint2*)bp;
  u16* qout = qkv;
  u16* kh = qkv + (size_t)T_ * D_;
  u16* vt = qkv + (size_t)2 * T_ * D_;
#pragma unroll 1
  for (int mat = 0; mat < 3; mat++) {
    uint2 bfrag[4][8];
#pragma unroll
    for (int nt = 0; nt < 4; nt++) {
      int ntg = wn * 4 + nt;
#pragma unroll
      for (int ks = 0; ks < 8; ks++)
        bfrag[nt][ks] = bpp[(mat * 64 + ntg * 8 + ks) * 64 + lane];
    }
    if (mat < 2) {
      // SWAPPED: D'[n][t]; lane: t = t0+wm*32+tt*16+l15, n = wn*64+nt*16+4*l4+i
      const float* bias = (mat == 0) ? bq : bk;
      f32x4 acc[4][2];
#pragma unroll
      for (int nt = 0; nt < 4; nt++) {
        float4 b4 = *(const float4*)(bias + wn * 64 + nt * 16 + l4 * 4);
        f32x4 bz = {b4.x, b4.y, b4.z, b4.w};
        acc[nt][0] = bz;
        acc[nt][1] = bz;
      }
#pragma unroll
      for (int kp = 0; kp < 4; kp++) {
#pragma unroll
        for (int nt = 0; nt < 4; nt++) {
          f16x8 a = cat8(bfrag[nt][2 * kp], bfrag[nt][2 * kp + 1]);
#pragma unroll
          for (int tt = 0; tt < 2; tt++) {
            f16x8 b = cat8(afr[tt][2 * kp], afr[tt][2 * kp + 1]);
            acc[nt][tt] = mfma32(a, b, acc[nt][tt]);
          }
        }
      }
#pragma unroll
      for (int tt = 0; tt < 2; tt++) {
        int tok = t0 + wm * 32 + tt * 16 + l15;
#pragma unroll
        for (int nt = 0; nt < 4; nt++) {
          int n0 = wn * 64 + nt * 16 + l4 * 4;
          f32x4 a = acc[nt][tt];
          uint2 pv = make_uint2(pack2h(a[0], a[1]), pack2h(a[2], a[3]));
          if (mat == 0) {
            *(uint2*)(qout + (size_t)tok * D_ + n0) = pv;
          } else {
            int bpi = tok >> 9, s = tok & 511;
            int ch = n0 >> 5, hd = n0 & 31;
            *(uint2*)(kh + ((size_t)(bpi * 4 + ch) * 512 + s) * 32 + hd) = pv;
          }
        }
      }
    } else {
      // ORIGINAL: D[t][n]; lane: t = t0+wm*32+mt*16+4*l4+i, n = wn*64+nt*16+l15
      f32x4 acc[2][4];
#pragma unroll
      for (int nt = 0; nt < 4; nt++) {
        float bvv = bv[wn * 64 + nt * 16 + l15];
#pragma unroll
        for (int mt = 0; mt < 2; mt++) {
          f32x4 z = {bvv, bvv, bvv, bvv};
          acc[mt][nt] = z;
        }
      }
#pragma unroll
      for (int kp = 0; kp < 4; kp++) {
#pragma unroll
        for (int mt = 0; mt < 2; mt++) {
          f16x8 a = cat8(afr[mt][2 * kp], afr[mt][2 * kp + 1]);
#pragma unroll
          for (int nt = 0; nt < 4; nt++) {
            f16x8 b = cat8(bfrag[nt][2 * kp], bfrag[nt][2 * kp + 1]);
            acc[mt][nt] = mfma32(a, b, acc[mt][nt]);
          }
        }
      }
#pragma unroll
      for (int mt = 0; mt < 2; mt++) {
        int rbase = t0 + wm * 32 + mt * 16 + (l4 << 2);
        int bpi = rbase >> 9;
        int s0 = rbase & 511;
#pragma unroll
        for (int nt = 0; nt < 4; nt++) {
          int col = wn * 64 + nt * 16 + l15;
          uint2 pv = make_uint2(pack2h(acc[mt][nt][0], acc[mt][nt][1]),
                                pack2h(acc[mt][nt][2], acc[mt][nt][3]));
          *(uint2*)(vt + ((size_t)(bpi * 4 + (col >> 5)) * 32 + (col & 31)) * 512 + s0) = pv;
        }
      }
    }
  }
}

// ---------------------------------------------------------------------------
// MFMA flash-attention (round-9 proven version): swapped operands, x32 MFMA.
// One block = (bp, h), 512 threads / 8 waves. Whole K (512x32) and V^T
// (32x512) staged in LDS once (64 KB) -> single barrier; waves free-run.
__global__ __launch_bounds__(512, 4) void attn_k(
    u16* wq_att, const u16* __restrict__ wk, const u16* __restrict__ wvt) {
  __shared__ __align__(16) u16 Ks[512 * 32];  // [k][32 hd], 8B-granule swizzle
  __shared__ __align__(16) u16 Vs[32 * 512];  // [hd][512 k], 8B-granule swizzle
  int tid = threadIdx.x;
  int bid = blockIdx.x;
  int h = bid & 3;
  int bp = bid >> 2;
  int lane = tid & 63, w = tid >> 6;
  int l15 = lane & 15, l4 = lane >> 4;
  size_t tbase = (size_t)bp * 512;
  int q0 = w * 64;
  // stage whole K (contiguous per-head) and V^T (contiguous)
  {
    const u16* kg = wk + (size_t)(bp * 4 + h) * 512 * 32;
    const u16* vg = wvt + (size_t)(bp * 4 + h) * 32 * 512;
#pragma unroll
    for (int j = 0; j < 4; j++) {
      int i = j * 512 + tid;
      uint4 ku = *(const uint4*)(kg + (size_t)i * 8);
      int row = i >> 2, c = i & 3;
      int swk = (row >> 1) & 7;
      *(uint2*)(Ks + row * 32 + (((2 * c)     ^ swk) << 2)) = make_uint2(ku.x, ku.y);
      *(uint2*)(Ks + row * 32 + (((2 * c + 1) ^ swk) << 2)) = make_uint2(ku.z, ku.w);
      uint4 vu = *(const uint4*)(vg + (size_t)i * 8);
      int vr2 = i >> 6, vc = i & 63;
      int swv = vr2 & 15;
      *(uint2*)(Vs + vr2 * 512 + (((2 * vc)     ^ swv) << 2)) = make_uint2(vu.x, vu.y);
      *(uint2*)(Vs + vr2 * 512 + (((2 * vc + 1) ^ swv) << 2)) = make_uint2(vu.z, vu.w);
    }
  }
  // Q B-frags (x32), pre-scaled by log2(e)/sqrt(32).
  uint4 qf8[4];
  {
    const u16* qbase = wq_att + (tbase + q0) * 128 + h * 32;
    const __half2 sc2 = __floats2half2_rn(0.25500527f, 0.25500527f);
#pragma unroll
    for (int nt = 0; nt < 4; nt++) {
      const u16* qr = qbase + (size_t)(nt * 16 + l15) * 128 + l4 * 4;
      uint2 u0 = *(const uint2*)(qr);
      uint2 u1 = *(const uint2*)(qr + 16);
      u32 w0 = __builtin_bit_cast(u32, __hmul2(__builtin_bit_cast(__half2, u0.x), sc2));
      u32 w1 = __builtin_bit_cast(u32, __hmul2(__builtin_bit_cast(__half2, u0.y), sc2));
      u32 w2 = __builtin_bit_cast(u32, __hmul2(__builtin_bit_cast(__half2, u1.x), sc2));
      u32 w3 = __builtin_bit_cast(u32, __hmul2(__builtin_bit_cast(__half2, u1.y), sc2));
      qf8[nt] = make_uint4(w0, w1, w2, w3);
    }
  }
  f32x4 O[2][4];
  f32x4 LS[4];
#pragma unroll
  for (int a = 0; a < 4; a++) {
    O[0][a] = (f32x4){0.f, 0.f, 0.f, 0.f};
    O[1][a] = (f32x4){0.f, 0.f, 0.f, 0.f};
    LS[a] = (f32x4){0.f, 0.f, 0.f, 0.f};
  }
  const f16x8 ones8 = {(_Float16)1.f, (_Float16)1.f, (_Float16)1.f, (_Float16)1.f,
                       (_Float16)1.f, (_Float16)1.f, (_Float16)1.f, (_Float16)1.f};
  __syncthreads();   // the only barrier

  for (int t0 = 0; t0 < 512; t0 += 64) {
#pragma unroll
    for (int mp = 0; mp < 2; mp++) {
      int krA = t0 + mp * 32 + l15;
      int krB = krA + 16;
      const u16* kpA = Ks + krA * 32;
      const u16* kpB = Ks + krB * 32;
      int swkA = (krA >> 1) & 7;
      int swkB = (krB >> 1) & 7;
      uint2 a0A = *(const uint2*)(kpA + ((l4       ^ swkA) << 2));
      uint2 a1A = *(const uint2*)(kpA + (((4 + l4) ^ swkA) << 2));
      uint2 a0B = *(const uint2*)(kpB + ((l4       ^ swkB) << 2));
      uint2 a1B = *(const uint2*)(kpB + (((4 + l4) ^ swkB) << 2));
      f16x8 a8A = cat8(a0A, a1A);
      f16x8 a8B = cat8(a0B, a1B);
      int gA = (t0 >> 2) + mp * 8 + l4;
      int gB = gA + 4;
      uint2 vA0 = *(const uint2*)(Vs + l15 * 512        + ((gA ^ l15) << 2));
      uint2 vB0 = *(const uint2*)(Vs + l15 * 512        + ((gB ^ l15) << 2));
      uint2 vA1 = *(const uint2*)(Vs + (16 + l15) * 512 + ((gA ^ l15) << 2));
      uint2 vB1 = *(const uint2*)(Vs + (16 + l15) * 512 + ((gB ^ l15) << 2));
      f16x8 v80 = cat8(vA0, vB0);
      f16x8 v81 = cat8(vA1, vB1);
      __builtin_amdgcn_s_setprio(1);
#pragma unroll
      for (int nt = 0; nt < 4; nt++) {
        f16x8 qb = __builtin_bit_cast(f16x8, qf8[nt]);
        f32x4 z = {0.f, 0.f, 0.f, 0.f};
        f32x4 sA = mfma32(a8A, qb, z);
        f32x4 sB = mfma32(a8B, qb, z);
        float e0 = __builtin_amdgcn_exp2f(sA[0]);
        float e1 = __builtin_amdgcn_exp2f(sA[1]);
        float e2 = __builtin_amdgcn_exp2f(sA[2]);
        float e3 = __builtin_amdgcn_exp2f(sA[3]);
        float e4 = __builtin_amdgcn_exp2f(sB[0]);
        float e5 = __builtin_amdgcn_exp2f(sB[1]);
        float e6 = __builtin_amdgcn_exp2f(sB[2]);
        float e7 = __builtin_amdgcn_exp2f(sB[3]);
        uint4 pu = make_uint4(
            __builtin_bit_cast(u32, __builtin_amdgcn_cvt_pkrtz(e0, e1)),
            __builtin_bit_cast(u32, __builtin_amdgcn_cvt_pkrtz(e2, e3)),
            __builtin_bit_cast(u32, __builtin_amdgcn_cvt_pkrtz(e4, e5)),
            __builtin_bit_cast(u32, __builtin_amdgcn_cvt_pkrtz(e6, e7)));
        f16x8 pb = __builtin_bit_cast(f16x8, pu);
        LS[nt]   = mfma32(ones8, pb, LS[nt]);
        O[0][nt] = mfma32(v80, pb, O[0][nt]);
        O[1][nt] = mfma32(v81, pb, O[1][nt]);
      }
      __builtin_amdgcn_s_setprio(0);
    }
  }
  // store att (overwrites this block's own q-rows / h-col slice only)
#pragma unroll
  for (int nt = 0; nt < 4; nt++) {
    float r = 1.f / LS[nt][0];
#pragma unroll
    for (int mt2 = 0; mt2 < 2; mt2++) {
      uint2 ov = make_uint2(pack2h(O[mt2][nt][0] * r, O[mt2][nt][1] * r),
                            pack2h(O[mt2][nt][2] * r, O[mt2][nt][3] * r));
      *(uint2*)(wq_att + (tbase + q0 + nt * 16 + l15) * 128 + h * 32 + mt2 * 16 + l4 * 4) = ov;
    }
  }
}

// ---------------------------------------------------------------------------
// Output projection, SWAPPED operands: D'[n][t], lane holds 4 consecutive n
// for one token -> dense uint2 stores of (att @ Wo^T + bo) into po[T][128].
// No mask, no atomics: masked slots are simply never gathered by ln_k.
__global__ __launch_bounds__(256) void proj_k(
    const u16* __restrict__ watt, const u16* __restrict__ bp, const float* __restrict__ bo,
    u16* __restrict__ po) {
  __shared__ uint4 As[64 * 16];
  int tid = threadIdx.x;
  int t0 = blockIdx.x * 64;
  {
    int r = tid >> 2, qd = tid & 3;
    const uint4* src = (const uint4*)(watt + (size_t)(t0 + r) * D_ + qd * 32);
#pragma unroll
    for (int c = 0; c < 4; c++) {
      int byteoff = (qd * 64 + c * 16) ^ ((r & 7) << 4);
      As[r * 16 + (byteoff >> 4)] = src[c];
    }
  }
  __syncthreads();
  int lane = tid & 63, wid = tid >> 6;
  int l15 = lane & 15, l4 = lane >> 4;
  int wm = wid & 1, wn = wid >> 1;
  uint2 bfrag[4][8];
  const uint2* bpp = (const uint2*)bp;
#pragma unroll
  for (int nt = 0; nt < 4; nt++) {
    int ntg = wn * 4 + nt;
#pragma unroll
    for (int ks = 0; ks < 8; ks++)
      bfrag[nt][ks] = bpp[(3 * 64 + ntg * 8 + ks) * 64 + lane];
  }
  uint2 afr[2][8];
#pragma unroll
  for (int tt = 0; tt < 2; tt++) {
    int row = wm * 32 + tt * 16 + l15;
#pragma unroll
    for (int ks = 0; ks < 8; ks++) {
      int byteoff = (ks * 32 + (l4 << 3)) ^ ((row & 7) << 4);
      afr[tt][ks] = *(const uint2*)((const char*)As + row * 256 + byteoff);
    }
  }
  // acc[nt][tt]: D'[n][t], n = wn*64+nt*16+4*l4+i, t = wm*32+tt*16+l15
  f32x4 acc[4][2];
#pragma unroll
  for (int nt = 0; nt < 4; nt++) {
    float4 bo4 = *(const float4*)(bo + wn * 64 + nt * 16 + l4 * 4);
    f32x4 bz = {bo4.x, bo4.y, bo4.z, bo4.w};
    acc[nt][0] = bz;
    acc[nt][1] = bz;
  }
#pragma unroll
  for (int kp = 0; kp < 4; kp++) {
#pragma unroll
    for (int nt = 0; nt < 4; nt++) {
      f16x8 a = cat8(bfrag[nt][2 * kp], bfrag[nt][2 * kp + 1]);
#pragma unroll
      for (int tt = 0; tt < 2; tt++) {
        f16x8 b = cat8(afr[tt][2 * kp], afr[tt][2 * kp + 1]);
        acc[nt][tt] = mfma32(a, b, acc[nt][tt]);
      }
    }
  }
#pragma unroll
  for (int tt = 0; tt < 2; tt++) {
    size_t tok = t0 + wm * 32 + tt * 16 + l15;
#pragma unroll
    for (int nt = 0; nt < 4; nt++) {
      int n0 = wn * 64 + nt * 16 + l4 * 4;
      f32x4 a = acc[nt][tt];
      uint2 pv = make_uint2(pack2h(a[0], a[1]), pack2h(a[2], a[3]));
      *(uint2*)(po + tok * D_ + n0) = pv;
    }
  }
}

// ---------------------------------------------------------------------------
// Gather-aggregate + residual + LayerNorm. Per (b,n) row: sum deg rows of po
// (fp32 accum) via the inverted index, h = x + sum/max(cnt,1), LN over D.
__global__ __launch_bounds__(256) void ln_k(
    const float* __restrict__ x, const int* __restrict__ cursor,
    const u16* __restrict__ po, const int* __restrict__ slots,
    const float* __restrict__ g, const float* __restrict__ bta, float* __restrict__ out) {
  int tid = threadIdx.x;
  int row = blockIdx.x * 8 + (tid >> 5);
  if (row >= B_ * N_) return;
  int l32 = tid & 31;
  int n = row % N_;
  int b = row / N_;
  int cnt = cursor[n];
  int deg = cnt > CAP_ ? CAP_ : cnt;
  float rc = 1.f / (float)(cnt > 1 ? cnt : 1);
  float4 a = make_float4(0.f, 0.f, 0.f, 0.f);
  const int* sl = slots + n * CAP_;
  for (int j = 0; j < deg; j++) {
    int s = sl[j];
    uint2 u = *(const uint2*)(po + ((size_t)b * PS_ + s) * D_ + l32 * 4);
    float2 a01 = __half22float2(__builtin_bit_cast(__half2, u.x));
    float2 a23 = __half22float2(__builtin_bit_cast(__half2, u.y));
    a.x += a01.x; a.y += a01.y; a.z += a23.x; a.w += a23.y;
  }
  size_t off = (size_t)row * D_ + l32 * 4;
  float4 xa = *(const float4*)(x + off);
  float4 hv = make_float4(fmaf(a.x, rc, xa.x), fmaf(a.y, rc, xa.y),
                          fmaf(a.z, rc, xa.z), fmaf(a.w, rc, xa.w));
  float s = hv.x + hv.y + hv.z + hv.w;
  float s2 = hv.x * hv.x + hv.y * hv.y + hv.z * hv.z + hv.w * hv.w;
#pragma unroll
  for (int m = 16; m >= 1; m >>= 1) {
    s += __shfl_xor(s, m);
    s2 += __shfl_xor(s2, m);
  }
  float mu = s * 0.0078125f;
  float var = s2 * 0.0078125f - mu * mu;
  float rstd = rsqrtf(var + 1e-5f);
  float4 gv = *(const float4*)(g + l32 * 4);
  float4 bv = *(const float4*)(bta + l32 * 4);
  float4 ov = make_float4((hv.x - mu) * rstd * gv.x + bv.x,
                          (hv.y - mu) * rstd * gv.y + bv.y,
                          (hv.z - mu) * rstd * gv.z + bv.z,
                          (hv.w - mu) * rstd * gv.w + bv.w);
  *(float4*)(out + off) = ov;
}

// ---------------------------------------------------------------------------
extern "C" void kernel_launch(void* const* d_in, const int* in_sizes, int n_in,
                              void* d_out, int out_size, void* d_ws, size_t ws_size,
                              hipStream_t stream) {
  const float* x   = (const float*)d_in[0];
  const float* Wq  = (const float*)d_in[1];
  const float* bq  = (const float*)d_in[2];
  const float* Wk  = (const float*)d_in[3];
  const float* bk  = (const float*)d_in[4];
  const float* Wv  = (const float*)d_in[5];
  const float* bv  = (const float*)d_in[6];
  const float* Wo  = (const float*)d_in[7];
  const float* bo  = (const float*)d_in[8];
  const float* lng = (const float*)d_in[9];
  const float* lnb = (const float*)d_in[10];
  const int* pidx  = (const int*)d_in[11];
  const void* cmask = d_in[12];
  float* out = (float*)d_out;
  char* ws = (char*)d_ws;

  u16* wsq = (u16*)(ws + OFF_Q);
  u16* wsk = (u16*)(ws + OFF_K);
  u16* wsvt = (u16*)(ws + OFF_V);
  u16* wbp = (u16*)(ws + OFF_BP);
  int* wflag  = (int*)(ws + OFF_FLAG);
  // after attn: K region -> po[T][128] fp16; V region -> cursor[N] + slots[N*CAP]
  u16* po = (u16*)(ws + OFF_K);
  int* cursor = (int*)(ws + OFF_V);
  int* slots = (int*)(ws + OFF_V + CUR_BYTES);

  hipMemsetAsync(wflag, 0, 4, stream);

  probe_mask_k<<<200, 256, 0, stream>>>((const unsigned char*)cmask, wflag);
  pack_w_k<<<64, 256, 0, stream>>>(Wq, Wk, Wv, Wo, wbp);
  qkv_k<<<1600, 256, 0, stream>>>(x, pidx, wbp, bq, bk, bv, wsq);
  attn_k<<<800, 512, 0, stream>>>(wsq, wsk, wsvt);
  // V region dead: build inverted index there (cursor doubles as cnt)
  hipMemsetAsync(cursor, 0, CUR_BYTES, stream);
  fill_k<<<200, 256, 0, stream>>>(cmask, pidx, wflag, cursor, slots);
  proj_k<<<1600, 256, 0, stream>>>(wsq, wbp, bo, po);
  ln_k<<<10241, 256, 0, stream>>>(x, cursor, po, slots, lng, lnb, out);
}

// Round 14
// 146.061 us; speedup vs baseline: 3.5961x; 1.0545x over previous
//
#include <hip/hip_runtime.h>
#include <hip/hip_bf16.h>
#include <hip/hip_fp16.h>

// Problem constants
#define B_ 2
#define N_ 40962
#define D_ 128
#define H_ 4
#define P_ 100
#define S_ 512
#define T_ 102400      // B*P*S tokens
#define PS_ 51200      // P*S
#define CAP_ 32        // inverted-index capacity per node

typedef unsigned short u16;
typedef unsigned int u32;
typedef _Float16 f16x4 __attribute__((ext_vector_type(4)));
typedef _Float16 f16x8 __attribute__((ext_vector_type(8)));
typedef float f32x4 __attribute__((ext_vector_type(4)));

// Workspace byte offsets (total ~79.2 MB)
#define OFF_Q    0ull           // q fp16 [T][128]  (later reused as att)
#define OFF_K    26214400ull    // k fp16 per-head [bp*4+h][512][32]; reused as po[T][128] fp16 after attn
#define OFF_V    52428800ull    // v fp16 V^T [bp*4+h][32][512]; reused as cursor[N]+slots[N*32] after attn
#define OFF_BP   78643200ull    // packed W frags: 4 mats x 4096 lane-frags x 8B
#define OFF_FLAG 79142920ull    // int dtype flag for core_mask
#define CUR_BYTES ((size_t)N_ * 4)

__device__ __forceinline__ u32 pack2h(float a, float b) {
  __half2 h = __floats2half2_rn(a, b);
  return __builtin_bit_cast(u32, h);
}
__device__ __forceinline__ f16x8 cat8(uint2 lo, uint2 hi) {
  return __builtin_bit_cast(f16x8, make_uint4(lo.x, lo.y, hi.x, hi.y));
}

// 16x16x32 f16 MFMA; x32 frag = concat of two x16 half-frags (k 0..15, 16..31).
__device__ __forceinline__ f32x4 mfma32(f16x8 a, f16x8 b, f32x4 c) {
#if __has_builtin(__builtin_amdgcn_mfma_f32_16x16x32_f16)
  return __builtin_amdgcn_mfma_f32_16x16x32_f16(a, b, c, 0, 0, 0);
#else
  f16x4 alo = {a[0], a[1], a[2], a[3]}, ahi = {a[4], a[5], a[6], a[7]};
  f16x4 blo = {b[0], b[1], b[2], b[3]}, bhi = {b[4], b[5], b[6], b[7]};
  c = __builtin_amdgcn_mfma_f32_16x16x16f16(alo, blo, c, 0, 0, 0);
  return __builtin_amdgcn_mfma_f32_16x16x16f16(ahi, bhi, c, 0, 0, 0);
#endif
}

__device__ __forceinline__ bool mask_on(const void* mask, int fl, int i) {
  if (fl & 1) return ((const unsigned char*)mask)[i] != 0;
  if (fl & 2) return ((const float*)mask)[i] != 0.f;
  return ((const int*)mask)[i] != 0;
}

// ---------------------------------------------------------------------------
// Probe core_mask storage format (bool8 / int32 / float32); wave-reduced OR.
__global__ void probe_mask_k(const unsigned char* __restrict__ mb, int* __restrict__ flag) {
  int i = blockIdx.x * 256 + threadIdx.x;
  int f = 0;
  unsigned char v = mb[i];
  if (v) {
    int m4 = i & 3;
    if (m4 == 1) f |= 1;
    else if (m4 == 3) f |= 2;
  }
#pragma unroll
  for (int m = 32; m >= 1; m >>= 1) f |= __shfl_xor(f, m);
  if ((threadIdx.x & 63) == 0 && f) atomicOr(flag, f);
}

// Build inverted index: for each masked slot ps, append to its node's list.
// cursor[n] doubles as the count (cnt) consumed by ln_k.
__global__ void fill_k(const void* __restrict__ mask, const int* __restrict__ pidx,
                       const int* __restrict__ flag, int* __restrict__ cursor,
                       int* __restrict__ slots) {
  int i = blockIdx.x * 256 + threadIdx.x;
  int fl = *flag;
  if (mask_on(mask, fl, i)) {
    int n = pidx[i];
    int pos = atomicAdd(&cursor[n], 1);
    if (pos < CAP_) slots[n * CAP_ + pos] = i;
  }
}

// ---------------------------------------------------------------------------
// Pack Wq/Wk/Wv/Wo into MFMA fragment order (fp16). Same bytes serve as
// B-operand (l15->n, 4*l4+i->k) and A-operand (l15->row n, 4*l4+i->k).
__global__ void pack_w_k(const float* __restrict__ Wq, const float* __restrict__ Wk,
                         const float* __restrict__ Wv, const float* __restrict__ Wo,
                         u16* __restrict__ bp) {
  int gi = blockIdx.x * 256 + threadIdx.x;   // < 16384
  int m = gi >> 12;
  int r = gi & 4095;
  int fi = r >> 6;         // nt*8 + ks
  int l = r & 63;
  int nt = fi >> 3, ks = fi & 7;
  const float* W = (m == 0) ? Wq : (m == 1) ? Wk : (m == 2) ? Wv : Wo;
  int n = nt * 16 + (l & 15);
  int k0 = ks * 16 + ((l >> 4) << 2);
  float4 w = *(const float4*)(W + n * 128 + k0);
  *(uint2*)(bp + (size_t)gi * 4) = make_uint2(pack2h(w.x, w.y), pack2h(w.z, w.w));
}

// ---------------------------------------------------------------------------
// QKV: r6 staging + swapped q/k compute + LDS-TRANSPOSED COALESCED STORES.
// Per mat: compute -> barrier -> ds_write acc in OUTPUT layout (8B-granule
// XOR swizzle) -> barrier -> flat readback: lane tid stores bytes
// [j*4096 + tid*16] of the block's 16KB output region => every global store
// instruction is full-line sequential (q: 4KB/instr; K: 16x64B rows; V: 8x128B runs).
__global__ __launch_bounds__(256) void qkv_k(
    const float* __restrict__ x, const int* __restrict__ pidx,
    const u16* __restrict__ bp,
    const float* __restrict__ bq, const float* __restrict__ bk, const float* __restrict__ bv,
    u16* __restrict__ qkv) {
  __shared__ uint4 As[64 * 16];   // 16KB: staging, then per-mat transpose buffer
  int tid = threadIdx.x;
  int t0 = blockIdx.x * 64;
  int bpi = t0 >> 9, s0 = t0 & 511;
  {
    int r = tid >> 2, qd = tid & 3;
    int T = t0 + r;
    int b = T / PS_;
    int ps = T - b * PS_;
    int pi = pidx[ps];
    const float4* src = (const float4*)(x + ((size_t)b * N_ + pi) * D_ + qd * 32);
    u32 us[16];
#pragma unroll
    for (int j = 0; j < 8; j++) {
      float4 f = src[j];
      us[2 * j]     = pack2h(f.x, f.y);
      us[2 * j + 1] = pack2h(f.z, f.w);
    }
#pragma unroll
    for (int c = 0; c < 4; c++) {
      int byteoff = (qd * 64 + c * 16) ^ ((r & 7) << 4);
      As[r * 16 + (byteoff >> 4)] = make_uint4(us[4 * c], us[4 * c + 1], us[4 * c + 2], us[4 * c + 3]);
    }
  }
  __syncthreads();
  int lane = tid & 63, wid = tid >> 6;
  int l15 = lane & 15, l4 = lane >> 4;
  int wm = wid & 1, wn = wid >> 1;
  uint2 afr[2][8];
#pragma unroll
  for (int tt = 0; tt < 2; tt++) {
    int row = wm * 32 + tt * 16 + l15;
#pragma unroll
    for (int ks = 0; ks < 8; ks++) {
      int byteoff = (ks * 32 + (l4 << 3)) ^ ((row & 7) << 4);
      afr[tt][ks] = *(const uint2*)((const char*)As + row * 256 + byteoff);
    }
  }
  const uint2* bpp = (const uint2*)bp;
  u16* qout = qkv;
  u16* kh = qkv + (size_t)T_ * D_;
  u16* vt = qkv + (size_t)2 * T_ * D_;
  char* Ab = (char*)As;
#pragma unroll 1
  for (int mat = 0; mat < 3; mat++) {
    uint2 bfrag[4][8];
#pragma unroll
    for (int nt = 0; nt < 4; nt++) {
      int ntg = wn * 4 + nt;
#pragma unroll
      for (int ks = 0; ks < 8; ks++)
        bfrag[nt][ks] = bpp[(mat * 64 + ntg * 8 + ks) * 64 + lane];
    }
    if (mat < 2) {
      // SWAPPED: D'[n][t]; lane: t = t0+wm*32+tt*16+l15, n = wn*64+nt*16+4*l4+i
      const float* bias = (mat == 0) ? bq : bk;
      f32x4 acc[4][2];
#pragma unroll
      for (int nt = 0; nt < 4; nt++) {
        float4 b4 = *(const float4*)(bias + wn * 64 + nt * 16 + l4 * 4);
        f32x4 bz = {b4.x, b4.y, b4.z, b4.w};
        acc[nt][0] = bz;
        acc[nt][1] = bz;
      }
#pragma unroll
      for (int kp = 0; kp < 4; kp++) {
#pragma unroll
        for (int nt = 0; nt < 4; nt++) {
          f16x8 a = cat8(bfrag[nt][2 * kp], bfrag[nt][2 * kp + 1]);
#pragma unroll
          for (int tt = 0; tt < 2; tt++) {
            f16x8 b = cat8(afr[tt][2 * kp], afr[tt][2 * kp + 1]);
            acc[nt][tt] = mfma32(a, b, acc[nt][tt]);
          }
        }
      }
      __syncthreads();   // As free (afr done / prior mat's readback done)
      if (mat == 0) {
        // q LDS layout: [t 64][256B row], 8B granule g=n0>>2, g^=(t&7) low 3 bits
#pragma unroll
        for (int tt = 0; tt < 2; tt++) {
          int t = wm * 32 + tt * 16 + l15;
#pragma unroll
          for (int nt = 0; nt < 4; nt++) {
            int n0 = wn * 64 + nt * 16 + l4 * 4;
            int g = n0 >> 2;
            int gp = (g & 24) | ((g & 7) ^ (t & 7));
            f32x4 a = acc[nt][tt];
            *(uint2*)(Ab + t * 256 + gp * 8) = make_uint2(pack2h(a[0], a[1]), pack2h(a[2], a[3]));
          }
        }
        __syncthreads();
#pragma unroll
        for (int j = 0; j < 4; j++) {
          int f = j * 4096 + tid * 16;
          int t = f >> 8, o = f & 255;
          int g = o >> 3, t7 = t & 7;
          int g0 = (g & 24) | ((g & 7) ^ t7);
          int g1 = (g & 24) | (((g & 7) + 1) ^ t7);
          uint2 ua = *(uint2*)(Ab + t * 256 + g0 * 8);
          uint2 ub = *(uint2*)(Ab + t * 256 + g1 * 8);
          *(uint4*)(qout + (size_t)(t0 + t) * D_ + (o >> 1)) = make_uint4(ua.x, ua.y, ub.x, ub.y);
        }
      } else {
        // K LDS layout: [ch 4][s 64][64B row], granule g=hd>>2 (0..7), g^=(s&7)
#pragma unroll
        for (int tt = 0; tt < 2; tt++) {
          int s = wm * 32 + tt * 16 + l15;
#pragma unroll
          for (int nt = 0; nt < 4; nt++) {
            int n0 = wn * 64 + nt * 16 + l4 * 4;
            int ch = n0 >> 5, hd = n0 & 31;
            int gp = (hd >> 2) ^ (s & 7);
            f32x4 a = acc[nt][tt];
            *(uint2*)(Ab + ch * 4096 + s * 64 + gp * 8) = make_uint2(pack2h(a[0], a[1]), pack2h(a[2], a[3]));
          }
        }
        __syncthreads();
#pragma unroll
        for (int j = 0; j < 4; j++) {
          int ch = j;
          int s = tid >> 2, o = (tid & 3) * 16;
          int g = o >> 3, s7 = s & 7;
          int g0 = g ^ s7;
          int g1 = (g + 1) ^ s7;
          uint2 ua = *(uint2*)(Ab + ch * 4096 + s * 64 + g0 * 8);
          uint2 ub = *(uint2*)(Ab + ch * 4096 + s * 64 + g1 * 8);
          *(uint4*)(kh + ((size_t)(bpi * 4 + ch) * 512 + s0 + s) * 32 + (o >> 1)) =
              make_uint4(ua.x, ua.y, ub.x, ub.y);
        }
      }
    } else {
      // ORIGINAL: D[t][n]; lane: t = t0+wm*32+mt*16+4*l4+i, n = wn*64+nt*16+l15
      f32x4 acc[2][4];
#pragma unroll
      for (int nt = 0; nt < 4; nt++) {
        float bvv = bv[wn * 64 + nt * 16 + l15];
#pragma unroll
        for (int mt = 0; mt < 2; mt++) {
          f32x4 z = {bvv, bvv, bvv, bvv};
          acc[mt][nt] = z;
        }
      }
#pragma unroll
      for (int kp = 0; kp < 4; kp++) {
#pragma unroll
        for (int mt = 0; mt < 2; mt++) {
          f16x8 a = cat8(afr[mt][2 * kp], afr[mt][2 * kp + 1]);
#pragma unroll
          for (int nt = 0; nt < 4; nt++) {
            f16x8 b = cat8(bfrag[nt][2 * kp], bfrag[nt][2 * kp + 1]);
            acc[mt][nt] = mfma32(a, b, acc[mt][nt]);
          }
        }
      }
      __syncthreads();   // As free
      // V LDS layout: [n 128][128B row of s], granule g=t>>2 (0..15), low3 ^= (n&7)
#pragma unroll
      for (int mt = 0; mt < 2; mt++) {
        int tl = wm * 32 + mt * 16 + l4 * 4;
        int g = tl >> 2;
#pragma unroll
        for (int nt = 0; nt < 4; nt++) {
          int n = wn * 64 + nt * 16 + l15;
          int gp = (g & 8) | ((g & 7) ^ (n & 7));
          f32x4 a = acc[mt][nt];
          *(uint2*)(Ab + n * 128 + gp * 8) = make_uint2(pack2h(a[0], a[1]), pack2h(a[2], a[3]));
        }
      }
      __syncthreads();
#pragma unroll
      for (int j = 0; j < 4; j++) {
        int f = j * 4096 + tid * 16;
        int n = f >> 7, o = f & 127;
        int g = o >> 3, n7 = n & 7;
        int g0 = (g & 8) | ((g & 7) ^ n7);
        int g1 = ((g + 1) & 8) | (((g + 1) & 7) ^ n7);
        uint2 ua = *(uint2*)(Ab + n * 128 + g0 * 8);
        uint2 ub = *(uint2*)(Ab + n * 128 + g1 * 8);
        int ch = n >> 5, hd = n & 31;
        *(uint4*)(vt + ((size_t)(bpi * 4 + ch) * 32 + hd) * 512 + s0 + (o >> 1)) =
            make_uint4(ua.x, ua.y, ub.x, ub.y);
      }
    }
  }
}

// ---------------------------------------------------------------------------
// MFMA flash-attention (round-9 proven version): swapped operands, x32 MFMA.
// One block = (bp, h), 512 threads / 8 waves. Whole K (512x32) and V^T
// (32x512) staged in LDS once (64 KB) -> single barrier; waves free-run.
__global__ __launch_bounds__(512, 4) void attn_k(
    u16* wq_att, const u16* __restrict__ wk, const u16* __restrict__ wvt) {
  __shared__ __align__(16) u16 Ks[512 * 32];  // [k][32 hd], 8B-granule swizzle
  __shared__ __align__(16) u16 Vs[32 * 512];  // [hd][512 k], 8B-granule swizzle
  int tid = threadIdx.x;
  int bid = blockIdx.x;
  int h = bid & 3;
  int bp = bid >> 2;
  int lane = tid & 63, w = tid >> 6;
  int l15 = lane & 15, l4 = lane >> 4;
  size_t tbase = (size_t)bp * 512;
  int q0 = w * 64;
  // stage whole K (contiguous per-head) and V^T (contiguous)
  {
    const u16* kg = wk + (size_t)(bp * 4 + h) * 512 * 32;
    const u16* vg = wvt + (size_t)(bp * 4 + h) * 32 * 512;
#pragma unroll
    for (int j = 0; j < 4; j++) {
      int i = j * 512 + tid;
      uint4 ku = *(const uint4*)(kg + (size_t)i * 8);
      int row = i >> 2, c = i & 3;
      int swk = (row >> 1) & 7;
      *(uint2*)(Ks + row * 32 + (((2 * c)     ^ swk) << 2)) = make_uint2(ku.x, ku.y);
      *(uint2*)(Ks + row * 32 + (((2 * c + 1) ^ swk) << 2)) = make_uint2(ku.z, ku.w);
      uint4 vu = *(const uint4*)(vg + (size_t)i * 8);
      int vr2 = i >> 6, vc = i & 63;
      int swv = vr2 & 15;
      *(uint2*)(Vs + vr2 * 512 + (((2 * vc)     ^ swv) << 2)) = make_uint2(vu.x, vu.y);
      *(uint2*)(Vs + vr2 * 512 + (((2 * vc + 1) ^ swv) << 2)) = make_uint2(vu.z, vu.w);
    }
  }
  // Q B-frags (x32), pre-scaled by log2(e)/sqrt(32).
  uint4 qf8[4];
  {
    const u16* qbase = wq_att + (tbase + q0) * 128 + h * 32;
    const __half2 sc2 = __floats2half2_rn(0.25500527f, 0.25500527f);
#pragma unroll
    for (int nt = 0; nt < 4; nt++) {
      const u16* qr = qbase + (size_t)(nt * 16 + l15) * 128 + l4 * 4;
      uint2 u0 = *(const uint2*)(qr);
      uint2 u1 = *(const uint2*)(qr + 16);
      u32 w0 = __builtin_bit_cast(u32, __hmul2(__builtin_bit_cast(__half2, u0.x), sc2));
      u32 w1 = __builtin_bit_cast(u32, __hmul2(__builtin_bit_cast(__half2, u0.y), sc2));
      u32 w2 = __builtin_bit_cast(u32, __hmul2(__builtin_bit_cast(__half2, u1.x), sc2));
      u32 w3 = __builtin_bit_cast(u32, __hmul2(__builtin_bit_cast(__half2, u1.y), sc2));
      qf8[nt] = make_uint4(w0, w1, w2, w3);
    }
  }
  f32x4 O[2][4];
  f32x4 LS[4];
#pragma unroll
  for (int a = 0; a < 4; a++) {
    O[0][a] = (f32x4){0.f, 0.f, 0.f, 0.f};
    O[1][a] = (f32x4){0.f, 0.f, 0.f, 0.f};
    LS[a] = (f32x4){0.f, 0.f, 0.f, 0.f};
  }
  const f16x8 ones8 = {(_Float16)1.f, (_Float16)1.f, (_Float16)1.f, (_Float16)1.f,
                       (_Float16)1.f, (_Float16)1.f, (_Float16)1.f, (_Float16)1.f};
  __syncthreads();   // the only barrier

  for (int t0 = 0; t0 < 512; t0 += 64) {
#pragma unroll
    for (int mp = 0; mp < 2; mp++) {
      int krA = t0 + mp * 32 + l15;
      int krB = krA + 16;
      const u16* kpA = Ks + krA * 32;
      const u16* kpB = Ks + krB * 32;
      int swkA = (krA >> 1) & 7;
      int swkB = (krB >> 1) & 7;
      uint2 a0A = *(const uint2*)(kpA + ((l4       ^ swkA) << 2));
      uint2 a1A = *(const uint2*)(kpA + (((4 + l4) ^ swkA) << 2));
      uint2 a0B = *(const uint2*)(kpB + ((l4       ^ swkB) << 2));
      uint2 a1B = *(const uint2*)(kpB + (((4 + l4) ^ swkB) << 2));
      f16x8 a8A = cat8(a0A, a1A);
      f16x8 a8B = cat8(a0B, a1B);
      int gA = (t0 >> 2) + mp * 8 + l4;
      int gB = gA + 4;
      uint2 vA0 = *(const uint2*)(Vs + l15 * 512        + ((gA ^ l15) << 2));
      uint2 vB0 = *(const uint2*)(Vs + l15 * 512        + ((gB ^ l15) << 2));
      uint2 vA1 = *(const uint2*)(Vs + (16 + l15) * 512 + ((gA ^ l15) << 2));
      uint2 vB1 = *(const uint2*)(Vs + (16 + l15) * 512 + ((gB ^ l15) << 2));
      f16x8 v80 = cat8(vA0, vB0);
      f16x8 v81 = cat8(vA1, vB1);
      __builtin_amdgcn_s_setprio(1);
#pragma unroll
      for (int nt = 0; nt < 4; nt++) {
        f16x8 qb = __builtin_bit_cast(f16x8, qf8[nt]);
        f32x4 z = {0.f, 0.f, 0.f, 0.f};
        f32x4 sA = mfma32(a8A, qb, z);
        f32x4 sB = mfma32(a8B, qb, z);
        float e0 = __builtin_amdgcn_exp2f(sA[0]);
        float e1 = __builtin_amdgcn_exp2f(sA[1]);
        float e2 = __builtin_amdgcn_exp2f(sA[2]);
        float e3 = __builtin_amdgcn_exp2f(sA[3]);
        float e4 = __builtin_amdgcn_exp2f(sB[0]);
        float e5 = __builtin_amdgcn_exp2f(sB[1]);
        float e6 = __builtin_amdgcn_exp2f(sB[2]);
        float e7 = __builtin_amdgcn_exp2f(sB[3]);
        uint4 pu = make_uint4(
            __builtin_bit_cast(u32, __builtin_amdgcn_cvt_pkrtz(e0, e1)),
            __builtin_bit_cast(u32, __builtin_amdgcn_cvt_pkrtz(e2, e3)),
            __builtin_bit_cast(u32, __builtin_amdgcn_cvt_pkrtz(e4, e5)),
            __builtin_bit_cast(u32, __builtin_amdgcn_cvt_pkrtz(e6, e7)));
        f16x8 pb = __builtin_bit_cast(f16x8, pu);
        LS[nt]   = mfma32(ones8, pb, LS[nt]);
        O[0][nt] = mfma32(v80, pb, O[0][nt]);
        O[1][nt] = mfma32(v81, pb, O[1][nt]);
      }
      __builtin_amdgcn_s_setprio(0);
    }
  }
  // store att (overwrites this block's own q-rows / h-col slice only)
#pragma unroll
  for (int nt = 0; nt < 4; nt++) {
    float r = 1.f / LS[nt][0];
#pragma unroll
    for (int mt2 = 0; mt2 < 2; mt2++) {
      uint2 ov = make_uint2(pack2h(O[mt2][nt][0] * r, O[mt2][nt][1] * r),
                            pack2h(O[mt2][nt][2] * r, O[mt2][nt][3] * r));
      *(uint2*)(wq_att + (tbase + q0 + nt * 16 + l15) * 128 + h * 32 + mt2 * 16 + l4 * 4) = ov;
    }
  }
}

// ---------------------------------------------------------------------------
// Output projection, SWAPPED operands: D'[n][t], lane holds 4 consecutive n
// for one token -> dense uint2 stores of (att @ Wo^T + bo) into po[T][128].
// No mask, no atomics: masked slots are simply never gathered by ln_k.
__global__ __launch_bounds__(256) void proj_k(
    const u16* __restrict__ watt, const u16* __restrict__ bp, const float* __restrict__ bo,
    u16* __restrict__ po) {
  __shared__ uint4 As[64 * 16];
  int tid = threadIdx.x;
  int t0 = blockIdx.x * 64;
  {
    int r = tid >> 2, qd = tid & 3;
    const uint4* src = (const uint4*)(watt + (size_t)(t0 + r) * D_ + qd * 32);
#pragma unroll
    for (int c = 0; c < 4; c++) {
      int byteoff = (qd * 64 + c * 16) ^ ((r & 7) << 4);
      As[r * 16 + (byteoff >> 4)] = src[c];
    }
  }
  __syncthreads();
  int lane = tid & 63, wid = tid >> 6;
  int l15 = lane & 15, l4 = lane >> 4;
  int wm = wid & 1, wn = wid >> 1;
  uint2 bfrag[4][8];
  const uint2* bpp = (const uint2*)bp;
#pragma unroll
  for (int nt = 0; nt < 4; nt++) {
    int ntg = wn * 4 + nt;
#pragma unroll
    for (int ks = 0; ks < 8; ks++)
      bfrag[nt][ks] = bpp[(3 * 64 + ntg * 8 + ks) * 64 + lane];
  }
  uint2 afr[2][8];
#pragma unroll
  for (int tt = 0; tt < 2; tt++) {
    int row = wm * 32 + tt * 16 + l15;
#pragma unroll
    for (int ks = 0; ks < 8; ks++) {
      int byteoff = (ks * 32 + (l4 << 3)) ^ ((row & 7) << 4);
      afr[tt][ks] = *(const uint2*)((const char*)As + row * 256 + byteoff);
    }
  }
  // acc[nt][tt]: D'[n][t], n = wn*64+nt*16+4*l4+i, t = wm*32+tt*16+l15
  f32x4 acc[4][2];
#pragma unroll
  for (int nt = 0; nt < 4; nt++) {
    float4 bo4 = *(const float4*)(bo + wn * 64 + nt * 16 + l4 * 4);
    f32x4 bz = {bo4.x, bo4.y, bo4.z, bo4.w};
    acc[nt][0] = bz;
    acc[nt][1] = bz;
  }
#pragma unroll
  for (int kp = 0; kp < 4; kp++) {
#pragma unroll
    for (int nt = 0; nt < 4; nt++) {
      f16x8 a = cat8(bfrag[nt][2 * kp], bfrag[nt][2 * kp + 1]);
#pragma unroll
      for (int tt = 0; tt < 2; tt++) {
        f16x8 b = cat8(afr[tt][2 * kp], afr[tt][2 * kp + 1]);
        acc[nt][tt] = mfma32(a, b, acc[nt][tt]);
      }
    }
  }
#pragma unroll
  for (int tt = 0; tt < 2; tt++) {
    size_t tok = t0 + wm * 32 + tt * 16 + l15;
#pragma unroll
    for (int nt = 0; nt < 4; nt++) {
      int n0 = wn * 64 + nt * 16 + l4 * 4;
      f32x4 a = acc[nt][tt];
      uint2 pv = make_uint2(pack2h(a[0], a[1]), pack2h(a[2], a[3]));
      *(uint2*)(po + tok * D_ + n0) = pv;
    }
  }
}

// ---------------------------------------------------------------------------
// Gather-aggregate + residual + LayerNorm. Per (b,n) row: sum deg rows of po
// (fp32 accum) via the inverted index, h = x + sum/max(cnt,1), LN over D.
__global__ __launch_bounds__(256) void ln_k(
    const float* __restrict__ x, const int* __restrict__ cursor,
    const u16* __restrict__ po, const int* __restrict__ slots,
    const float* __restrict__ g, const float* __restrict__ bta, float* __restrict__ out) {
  int tid = threadIdx.x;
  int row = blockIdx.x * 8 + (tid >> 5);
  if (row >= B_ * N_) return;
  int l32 = tid & 31;
  int n = row % N_;
  int b = row / N_;
  int cnt = cursor[n];
  int deg = cnt > CAP_ ? CAP_ : cnt;
  float rc = 1.f / (float)(cnt > 1 ? cnt : 1);
  float4 a = make_float4(0.f, 0.f, 0.f, 0.f);
  const int* sl = slots + n * CAP_;
  for (int j = 0; j < deg; j++) {
    int s = sl[j];
    uint2 u = *(const uint2*)(po + ((size_t)b * PS_ + s) * D_ + l32 * 4);
    float2 a01 = __half22float2(__builtin_bit_cast(__half2, u.x));
    float2 a23 = __half22float2(__builtin_bit_cast(__half2, u.y));
    a.x += a01.x; a.y += a01.y; a.z += a23.x; a.w += a23.y;
  }
  size_t off = (size_t)row * D_ + l32 * 4;
  float4 xa = *(const float4*)(x + off);
  float4 hv = make_float4(fmaf(a.x, rc, xa.x), fmaf(a.y, rc, xa.y),
                          fmaf(a.z, rc, xa.z), fmaf(a.w, rc, xa.w));
  float s = hv.x + hv.y + hv.z + hv.w;
  float s2 = hv.x * hv.x + hv.y * hv.y + hv.z * hv.z + hv.w * hv.w;
#pragma unroll
  for (int m = 16; m >= 1; m >>= 1) {
    s += __shfl_xor(s, m);
    s2 += __shfl_xor(s2, m);
  }
  float mu = s * 0.0078125f;
  float var = s2 * 0.0078125f - mu * mu;
  float rstd = rsqrtf(var + 1e-5f);
  float4 gv = *(const float4*)(g + l32 * 4);
  float4 bv = *(const float4*)(bta + l32 * 4);
  float4 ov = make_float4((hv.x - mu) * rstd * gv.x + bv.x,
                          (hv.y - mu) * rstd * gv.y + bv.y,
                          (hv.z - mu) * rstd * gv.z + bv.z,
                          (hv.w - mu) * rstd * gv.w + bv.w);
  *(float4*)(out + off) = ov;
}

// ---------------------------------------------------------------------------
extern "C" void kernel_launch(void* const* d_in, const int* in_sizes, int n_in,
                              void* d_out, int out_size, void* d_ws, size_t ws_size,
                              hipStream_t stream) {
  const float* x   = (const float*)d_in[0];
  const float* Wq  = (const float*)d_in[1];
  const float* bq  = (const float*)d_in[2];
  const float* Wk  = (const float*)d_in[3];
  const float* bk  = (const float*)d_in[4];
  const float* Wv  = (const float*)d_in[5];
  const float* bv  = (const float*)d_in[6];
  const float* Wo  = (const float*)d_in[7];
  const float* bo  = (const float*)d_in[8];
  const float* lng = (const float*)d_in[9];
  const float* lnb = (const float*)d_in[10];
  const int* pidx  = (const int*)d_in[11];
  const void* cmask = d_in[12];
  float* out = (float*)d_out;
  char* ws = (char*)d_ws;

  u16* wsq = (u16*)(ws + OFF_Q);
  u16* wsk = (u16*)(ws + OFF_K);
  u16* wsvt = (u16*)(ws + OFF_V);
  u16* wbp = (u16*)(ws + OFF_BP);
  int* wflag  = (int*)(ws + OFF_FLAG);
  // after attn: K region -> po[T][128] fp16; V region -> cursor[N] + slots[N*CAP]
  u16* po = (u16*)(ws + OFF_K);
  int* cursor = (int*)(ws + OFF_V);
  int* slots = (int*)(ws + OFF_V + CUR_BYTES);

  hipMemsetAsync(wflag, 0, 4, stream);

  probe_mask_k<<<200, 256, 0, stream>>>((const unsigned char*)cmask, wflag);
  pack_w_k<<<64, 256, 0, stream>>>(Wq, Wk, Wv, Wo, wbp);
  qkv_k<<<1600, 256, 0, stream>>>(x, pidx, wbp, bq, bk, bv, wsq);
  attn_k<<<800, 512, 0, stream>>>(wsq, wsk, wsvt);
  // V region dead: build inverted index there (cursor doubles as cnt)
  hipMemsetAsync(cursor, 0, CUR_BYTES, stream);
  fill_k<<<200, 256, 0, stream>>>(cmask, pidx, wflag, cursor, slots);
  proj_k<<<1600, 256, 0, stream>>>(wsq, wbp, bo, po);
  ln_k<<<10241, 256, 0, stream>>>(x, cursor, po, slots, lng, lnb, out);
}

// Round 15
// 143.444 us; speedup vs baseline: 3.6617x; 1.0182x over previous
//
#include <hip/hip_runtime.h>
#include <hip/hip_bf16.h>
#include <hip/hip_fp16.h>

// Problem constants
#define B_ 2
#define N_ 40962
#define D_ 128
#define H_ 4
#define P_ 100
#define S_ 512
#define T_ 102400      // B*P*S tokens
#define PS_ 51200      // P*S
#define CAP_ 32        // inverted-index capacity per node

typedef unsigned short u16;
typedef unsigned int u32;
typedef _Float16 f16x4 __attribute__((ext_vector_type(4)));
typedef _Float16 f16x8 __attribute__((ext_vector_type(8)));
typedef float f32x4 __attribute__((ext_vector_type(4)));

// Workspace byte offsets (total ~79.2 MB)
#define OFF_Q    0ull           // q fp16 [T][128]  (later reused as att)
#define OFF_K    26214400ull    // k fp16 per-head [bp*4+h][512][32]; reused as po[T][128] fp16 after attn
#define OFF_V    52428800ull    // v fp16 V^T [bp*4+h][32][512]; reused as cursor[N]+slots[N*32] after attn
#define OFF_BP   78643200ull    // packed W frags: 4 mats x 4096 lane-frags x 8B
#define OFF_FLAG 79142920ull    // int dtype flag for core_mask
#define CUR_BYTES ((size_t)N_ * 4)

__device__ __forceinline__ u32 pack2h(float a, float b) {
  __half2 h = __floats2half2_rn(a, b);
  return __builtin_bit_cast(u32, h);
}
__device__ __forceinline__ f16x8 cat8(uint2 lo, uint2 hi) {
  return __builtin_bit_cast(f16x8, make_uint4(lo.x, lo.y, hi.x, hi.y));
}

// 16x16x32 f16 MFMA; x32 frag = concat of two x16 half-frags (k 0..15, 16..31).
__device__ __forceinline__ f32x4 mfma32(f16x8 a, f16x8 b, f32x4 c) {
#if __has_builtin(__builtin_amdgcn_mfma_f32_16x16x32_f16)
  return __builtin_amdgcn_mfma_f32_16x16x32_f16(a, b, c, 0, 0, 0);
#else
  f16x4 alo = {a[0], a[1], a[2], a[3]}, ahi = {a[4], a[5], a[6], a[7]};
  f16x4 blo = {b[0], b[1], b[2], b[3]}, bhi = {b[4], b[5], b[6], b[7]};
  c = __builtin_amdgcn_mfma_f32_16x16x16f16(alo, blo, c, 0, 0, 0);
  return __builtin_amdgcn_mfma_f32_16x16x16f16(ahi, bhi, c, 0, 0, 0);
#endif
}

__device__ __forceinline__ bool mask_on(const void* mask, int fl, int i) {
  if (fl & 1) return ((const unsigned char*)mask)[i] != 0;
  if (fl & 2) return ((const float*)mask)[i] != 0.f;
  return ((const int*)mask)[i] != 0;
}

// ---------------------------------------------------------------------------
// Probe core_mask storage format (bool8 / int32 / float32); wave-reduced OR.
__global__ void probe_mask_k(const unsigned char* __restrict__ mb, int* __restrict__ flag) {
  int i = blockIdx.x * 256 + threadIdx.x;
  int f = 0;
  unsigned char v = mb[i];
  if (v) {
    int m4 = i & 3;
    if (m4 == 1) f |= 1;
    else if (m4 == 3) f |= 2;
  }
#pragma unroll
  for (int m = 32; m >= 1; m >>= 1) f |= __shfl_xor(f, m);
  if ((threadIdx.x & 63) == 0 && f) atomicOr(flag, f);
}

// Build inverted index: for each masked slot ps, append to its node's list.
// cursor[n] doubles as the count (cnt) consumed by ln_k.
__global__ void fill_k(const void* __restrict__ mask, const int* __restrict__ pidx,
                       const int* __restrict__ flag, int* __restrict__ cursor,
                       int* __restrict__ slots) {
  int i = blockIdx.x * 256 + threadIdx.x;
  int fl = *flag;
  if (mask_on(mask, fl, i)) {
    int n = pidx[i];
    int pos = atomicAdd(&cursor[n], 1);
    if (pos < CAP_) slots[n * CAP_ + pos] = i;
  }
}

// ---------------------------------------------------------------------------
// Pack Wq/Wk/Wv/Wo into MFMA fragment order (fp16). Same bytes serve as
// B-operand (l15->n, 4*l4+i->k) and A-operand (l15->row n, 4*l4+i->k).
__global__ void pack_w_k(const float* __restrict__ Wq, const float* __restrict__ Wk,
                         const float* __restrict__ Wv, const float* __restrict__ Wo,
                         u16* __restrict__ bp) {
  int gi = blockIdx.x * 256 + threadIdx.x;   // < 16384
  int m = gi >> 12;
  int r = gi & 4095;
  int fi = r >> 6;         // nt*8 + ks
  int l = r & 63;
  int nt = fi >> 3, ks = fi & 7;
  const float* W = (m == 0) ? Wq : (m == 1) ? Wk : (m == 2) ? Wv : Wo;
  int n = nt * 16 + (l & 15);
  int k0 = ks * 16 + ((l >> 4) << 2);
  float4 w = *(const float4*)(W + n * 128 + k0);
  *(uint2*)(bp + (size_t)gi * 4) = make_uint2(pack2h(w.x, w.y), pack2h(w.z, w.w));
}

// ---------------------------------------------------------------------------
// QKV: r6 staging + swapped q/k compute + LDS-transposed coalesced stores
// (round-14 proven). Per mat: compute -> barrier -> ds_write acc in OUTPUT
// layout (8B-granule XOR swizzle) -> barrier -> full-line flat readback.
__global__ __launch_bounds__(256) void qkv_k(
    const float* __restrict__ x, const int* __restrict__ pidx,
    const u16* __restrict__ bp,
    const float* __restrict__ bq, const float* __restrict__ bk, const float* __restrict__ bv,
    u16* __restrict__ qkv) {
  __shared__ uint4 As[64 * 16];   // 16KB: staging, then per-mat transpose buffer
  int tid = threadIdx.x;
  int t0 = blockIdx.x * 64;
  int bpi = t0 >> 9, s0 = t0 & 511;
  {
    int r = tid >> 2, qd = tid & 3;
    int T = t0 + r;
    int b = T / PS_;
    int ps = T - b * PS_;
    int pi = pidx[ps];
    const float4* src = (const float4*)(x + ((size_t)b * N_ + pi) * D_ + qd * 32);
    u32 us[16];
#pragma unroll
    for (int j = 0; j < 8; j++) {
      float4 f = src[j];
      us[2 * j]     = pack2h(f.x, f.y);
      us[2 * j + 1] = pack2h(f.z, f.w);
    }
#pragma unroll
    for (int c = 0; c < 4; c++) {
      int byteoff = (qd * 64 + c * 16) ^ ((r & 7) << 4);
      As[r * 16 + (byteoff >> 4)] = make_uint4(us[4 * c], us[4 * c + 1], us[4 * c + 2], us[4 * c + 3]);
    }
  }
  __syncthreads();
  int lane = tid & 63, wid = tid >> 6;
  int l15 = lane & 15, l4 = lane >> 4;
  int wm = wid & 1, wn = wid >> 1;
  uint2 afr[2][8];
#pragma unroll
  for (int tt = 0; tt < 2; tt++) {
    int row = wm * 32 + tt * 16 + l15;
#pragma unroll
    for (int ks = 0; ks < 8; ks++) {
      int byteoff = (ks * 32 + (l4 << 3)) ^ ((row & 7) << 4);
      afr[tt][ks] = *(const uint2*)((const char*)As + row * 256 + byteoff);
    }
  }
  const uint2* bpp = (const uint2*)bp;
  u16* qout = qkv;
  u16* kh = qkv + (size_t)T_ * D_;
  u16* vt = qkv + (size_t)2 * T_ * D_;
  char* Ab = (char*)As;
#pragma unroll 1
  for (int mat = 0; mat < 3; mat++) {
    uint2 bfrag[4][8];
#pragma unroll
    for (int nt = 0; nt < 4; nt++) {
      int ntg = wn * 4 + nt;
#pragma unroll
      for (int ks = 0; ks < 8; ks++)
        bfrag[nt][ks] = bpp[(mat * 64 + ntg * 8 + ks) * 64 + lane];
    }
    if (mat < 2) {
      // SWAPPED: D'[n][t]; lane: t = t0+wm*32+tt*16+l15, n = wn*64+nt*16+4*l4+i
      const float* bias = (mat == 0) ? bq : bk;
      f32x4 acc[4][2];
#pragma unroll
      for (int nt = 0; nt < 4; nt++) {
        float4 b4 = *(const float4*)(bias + wn * 64 + nt * 16 + l4 * 4);
        f32x4 bz = {b4.x, b4.y, b4.z, b4.w};
        acc[nt][0] = bz;
        acc[nt][1] = bz;
      }
#pragma unroll
      for (int kp = 0; kp < 4; kp++) {
#pragma unroll
        for (int nt = 0; nt < 4; nt++) {
          f16x8 a = cat8(bfrag[nt][2 * kp], bfrag[nt][2 * kp + 1]);
#pragma unroll
          for (int tt = 0; tt < 2; tt++) {
            f16x8 b = cat8(afr[tt][2 * kp], afr[tt][2 * kp + 1]);
            acc[nt][tt] = mfma32(a, b, acc[nt][tt]);
          }
        }
      }
      __syncthreads();   // As free (afr done / prior mat's readback done)
      if (mat == 0) {
        // q LDS layout: [t 64][256B row], 8B granule g=n0>>2, g^=(t&7) low 3 bits
#pragma unroll
        for (int tt = 0; tt < 2; tt++) {
          int t = wm * 32 + tt * 16 + l15;
#pragma unroll
          for (int nt = 0; nt < 4; nt++) {
            int n0 = wn * 64 + nt * 16 + l4 * 4;
            int g = n0 >> 2;
            int gp = (g & 24) | ((g & 7) ^ (t & 7));
            f32x4 a = acc[nt][tt];
            *(uint2*)(Ab + t * 256 + gp * 8) = make_uint2(pack2h(a[0], a[1]), pack2h(a[2], a[3]));
          }
        }
        __syncthreads();
#pragma unroll
        for (int j = 0; j < 4; j++) {
          int f = j * 4096 + tid * 16;
          int t = f >> 8, o = f & 255;
          int g = o >> 3, t7 = t & 7;
          int g0 = (g & 24) | ((g & 7) ^ t7);
          int g1 = (g & 24) | (((g & 7) + 1) ^ t7);
          uint2 ua = *(uint2*)(Ab + t * 256 + g0 * 8);
          uint2 ub = *(uint2*)(Ab + t * 256 + g1 * 8);
          *(uint4*)(qout + (size_t)(t0 + t) * D_ + (o >> 1)) = make_uint4(ua.x, ua.y, ub.x, ub.y);
        }
      } else {
        // K LDS layout: [ch 4][s 64][64B row], granule g=hd>>2 (0..7), g^=(s&7)
#pragma unroll
        for (int tt = 0; tt < 2; tt++) {
          int s = wm * 32 + tt * 16 + l15;
#pragma unroll
          for (int nt = 0; nt < 4; nt++) {
            int n0 = wn * 64 + nt * 16 + l4 * 4;
            int ch = n0 >> 5, hd = n0 & 31;
            int gp = (hd >> 2) ^ (s & 7);
            f32x4 a = acc[nt][tt];
            *(uint2*)(Ab + ch * 4096 + s * 64 + gp * 8) = make_uint2(pack2h(a[0], a[1]), pack2h(a[2], a[3]));
          }
        }
        __syncthreads();
#pragma unroll
        for (int j = 0; j < 4; j++) {
          int ch = j;
          int s = tid >> 2, o = (tid & 3) * 16;
          int g = o >> 3, s7 = s & 7;
          int g0 = g ^ s7;
          int g1 = (g + 1) ^ s7;
          uint2 ua = *(uint2*)(Ab + ch * 4096 + s * 64 + g0 * 8);
          uint2 ub = *(uint2*)(Ab + ch * 4096 + s * 64 + g1 * 8);
          *(uint4*)(kh + ((size_t)(bpi * 4 + ch) * 512 + s0 + s) * 32 + (o >> 1)) =
              make_uint4(ua.x, ua.y, ub.x, ub.y);
        }
      }
    } else {
      // ORIGINAL: D[t][n]; lane: t = t0+wm*32+mt*16+4*l4+i, n = wn*64+nt*16+l15
      f32x4 acc[2][4];
#pragma unroll
      for (int nt = 0; nt < 4; nt++) {
        float bvv = bv[wn * 64 + nt * 16 + l15];
#pragma unroll
        for (int mt = 0; mt < 2; mt++) {
          f32x4 z = {bvv, bvv, bvv, bvv};
          acc[mt][nt] = z;
        }
      }
#pragma unroll
      for (int kp = 0; kp < 4; kp++) {
#pragma unroll
        for (int mt = 0; mt < 2; mt++) {
          f16x8 a = cat8(afr[mt][2 * kp], afr[mt][2 * kp + 1]);
#pragma unroll
          for (int nt = 0; nt < 4; nt++) {
            f16x8 b = cat8(bfrag[nt][2 * kp], bfrag[nt][2 * kp + 1]);
            acc[mt][nt] = mfma32(a, b, acc[mt][nt]);
          }
        }
      }
      __syncthreads();   // As free
      // V LDS layout: [n 128][128B row of s], granule g=t>>2 (0..15), low3 ^= (n&7)
#pragma unroll
      for (int mt = 0; mt < 2; mt++) {
        int tl = wm * 32 + mt * 16 + l4 * 4;
        int g = tl >> 2;
#pragma unroll
        for (int nt = 0; nt < 4; nt++) {
          int n = wn * 64 + nt * 16 + l15;
          int gp = (g & 8) | ((g & 7) ^ (n & 7));
          f32x4 a = acc[mt][nt];
          *(uint2*)(Ab + n * 128 + gp * 8) = make_uint2(pack2h(a[0], a[1]), pack2h(a[2], a[3]));
        }
      }
      __syncthreads();
#pragma unroll
      for (int j = 0; j < 4; j++) {
        int f = j * 4096 + tid * 16;
        int n = f >> 7, o = f & 127;
        int g = o >> 3, n7 = n & 7;
        int g0 = (g & 8) | ((g & 7) ^ n7);
        int g1 = ((g + 1) & 8) | (((g + 1) & 7) ^ n7);
        uint2 ua = *(uint2*)(Ab + n * 128 + g0 * 8);
        uint2 ub = *(uint2*)(Ab + n * 128 + g1 * 8);
        int ch = n >> 5, hd = n & 31;
        *(uint4*)(vt + ((size_t)(bpi * 4 + ch) * 32 + hd) * 512 + s0 + (o >> 1)) =
            make_uint4(ua.x, ua.y, ub.x, ub.y);
      }
    }
  }
}

// ---------------------------------------------------------------------------
// MFMA flash-attention, swapped operands, x32 MFMA. One block = (bp, h),
// 512 threads / 8 waves. Whole K + V^T staged in LDS once (64 KB), single
// barrier. ILP-batched inner loop: per mp, phase 1 = 8 independent QK MFMAs,
// phase 2 = 32 exps + packs, phase 3 = 16 PV/LS MFMAs — maximizes per-wave
// independent-op batches for the scheduler (VGPR ~95 < 128 cap, no spill).
__global__ __launch_bounds__(512, 4) void attn_k(
    u16* wq_att, const u16* __restrict__ wk, const u16* __restrict__ wvt) {
  __shared__ __align__(16) u16 Ks[512 * 32];  // [k][32 hd], 8B-granule swizzle
  __shared__ __align__(16) u16 Vs[32 * 512];  // [hd][512 k], 8B-granule swizzle
  int tid = threadIdx.x;
  int bid = blockIdx.x;
  int h = bid & 3;
  int bp = bid >> 2;
  int lane = tid & 63, w = tid >> 6;
  int l15 = lane & 15, l4 = lane >> 4;
  size_t tbase = (size_t)bp * 512;
  int q0 = w * 64;
  // stage whole K (contiguous per-head) and V^T (contiguous)
  {
    const u16* kg = wk + (size_t)(bp * 4 + h) * 512 * 32;
    const u16* vg = wvt + (size_t)(bp * 4 + h) * 32 * 512;
#pragma unroll
    for (int j = 0; j < 4; j++) {
      int i = j * 512 + tid;
      uint4 ku = *(const uint4*)(kg + (size_t)i * 8);
      int row = i >> 2, c = i & 3;
      int swk = (row >> 1) & 7;
      *(uint2*)(Ks + row * 32 + (((2 * c)     ^ swk) << 2)) = make_uint2(ku.x, ku.y);
      *(uint2*)(Ks + row * 32 + (((2 * c + 1) ^ swk) << 2)) = make_uint2(ku.z, ku.w);
      uint4 vu = *(const uint4*)(vg + (size_t)i * 8);
      int vr2 = i >> 6, vc = i & 63;
      int swv = vr2 & 15;
      *(uint2*)(Vs + vr2 * 512 + (((2 * vc)     ^ swv) << 2)) = make_uint2(vu.x, vu.y);
      *(uint2*)(Vs + vr2 * 512 + (((2 * vc + 1) ^ swv) << 2)) = make_uint2(vu.z, vu.w);
    }
  }
  // Q B-frags (x32), pre-scaled by log2(e)/sqrt(32).
  uint4 qf8[4];
  {
    const u16* qbase = wq_att + (tbase + q0) * 128 + h * 32;
    const __half2 sc2 = __floats2half2_rn(0.25500527f, 0.25500527f);
#pragma unroll
    for (int nt = 0; nt < 4; nt++) {
      const u16* qr = qbase + (size_t)(nt * 16 + l15) * 128 + l4 * 4;
      uint2 u0 = *(const uint2*)(qr);
      uint2 u1 = *(const uint2*)(qr + 16);
      u32 w0 = __builtin_bit_cast(u32, __hmul2(__builtin_bit_cast(__half2, u0.x), sc2));
      u32 w1 = __builtin_bit_cast(u32, __hmul2(__builtin_bit_cast(__half2, u0.y), sc2));
      u32 w2 = __builtin_bit_cast(u32, __hmul2(__builtin_bit_cast(__half2, u1.x), sc2));
      u32 w3 = __builtin_bit_cast(u32, __hmul2(__builtin_bit_cast(__half2, u1.y), sc2));
      qf8[nt] = make_uint4(w0, w1, w2, w3);
    }
  }
  f32x4 O[2][4];
  f32x4 LS[4];
#pragma unroll
  for (int a = 0; a < 4; a++) {
    O[0][a] = (f32x4){0.f, 0.f, 0.f, 0.f};
    O[1][a] = (f32x4){0.f, 0.f, 0.f, 0.f};
    LS[a] = (f32x4){0.f, 0.f, 0.f, 0.f};
  }
  const f16x8 ones8 = {(_Float16)1.f, (_Float16)1.f, (_Float16)1.f, (_Float16)1.f,
                       (_Float16)1.f, (_Float16)1.f, (_Float16)1.f, (_Float16)1.f};
  __syncthreads();   // the only barrier

  for (int t0 = 0; t0 < 512; t0 += 64) {
#pragma unroll
    for (int mp = 0; mp < 2; mp++) {
      int krA = t0 + mp * 32 + l15;
      int krB = krA + 16;
      const u16* kpA = Ks + krA * 32;
      const u16* kpB = Ks + krB * 32;
      int swkA = (krA >> 1) & 7;
      int swkB = (krB >> 1) & 7;
      uint2 a0A = *(const uint2*)(kpA + ((l4       ^ swkA) << 2));
      uint2 a1A = *(const uint2*)(kpA + (((4 + l4) ^ swkA) << 2));
      uint2 a0B = *(const uint2*)(kpB + ((l4       ^ swkB) << 2));
      uint2 a1B = *(const uint2*)(kpB + (((4 + l4) ^ swkB) << 2));
      f16x8 a8A = cat8(a0A, a1A);
      f16x8 a8B = cat8(a0B, a1B);
      int gA = (t0 >> 2) + mp * 8 + l4;
      int gB = gA + 4;
      uint2 vA0 = *(const uint2*)(Vs + l15 * 512        + ((gA ^ l15) << 2));
      uint2 vB0 = *(const uint2*)(Vs + l15 * 512        + ((gB ^ l15) << 2));
      uint2 vA1 = *(const uint2*)(Vs + (16 + l15) * 512 + ((gA ^ l15) << 2));
      uint2 vB1 = *(const uint2*)(Vs + (16 + l15) * 512 + ((gB ^ l15) << 2));
      f16x8 v80 = cat8(vA0, vB0);
      f16x8 v81 = cat8(vA1, vB1);
      __builtin_amdgcn_s_setprio(1);
      // phase 1: all 8 QK MFMAs (independent)
      f32x4 S[4][2];
#pragma unroll
      for (int nt = 0; nt < 4; nt++) {
        f16x8 qb = __builtin_bit_cast(f16x8, qf8[nt]);
        f32x4 z = {0.f, 0.f, 0.f, 0.f};
        S[nt][0] = mfma32(a8A, qb, z);
        S[nt][1] = mfma32(a8B, qb, z);
      }
      // phase 2: all 32 exps + packs (independent)
      uint4 pu[4];
#pragma unroll
      for (int nt = 0; nt < 4; nt++) {
        float e0 = __builtin_amdgcn_exp2f(S[nt][0][0]);
        float e1 = __builtin_amdgcn_exp2f(S[nt][0][1]);
        float e2 = __builtin_amdgcn_exp2f(S[nt][0][2]);
        float e3 = __builtin_amdgcn_exp2f(S[nt][0][3]);
        float e4 = __builtin_amdgcn_exp2f(S[nt][1][0]);
        float e5 = __builtin_amdgcn_exp2f(S[nt][1][1]);
        float e6 = __builtin_amdgcn_exp2f(S[nt][1][2]);
        float e7 = __builtin_amdgcn_exp2f(S[nt][1][3]);
        pu[nt] = make_uint4(
            __builtin_bit_cast(u32, __builtin_amdgcn_cvt_pkrtz(e0, e1)),
            __builtin_bit_cast(u32, __builtin_amdgcn_cvt_pkrtz(e2, e3)),
            __builtin_bit_cast(u32, __builtin_amdgcn_cvt_pkrtz(e4, e5)),
            __builtin_bit_cast(u32, __builtin_amdgcn_cvt_pkrtz(e6, e7)));
      }
      // phase 3: all 16 PV/LS MFMAs (independent accumulator chains)
#pragma unroll
      for (int nt = 0; nt < 4; nt++) {
        f16x8 pb = __builtin_bit_cast(f16x8, pu[nt]);
        LS[nt]   = mfma32(ones8, pb, LS[nt]);
        O[0][nt] = mfma32(v80, pb, O[0][nt]);
        O[1][nt] = mfma32(v81, pb, O[1][nt]);
      }
      __builtin_amdgcn_s_setprio(0);
    }
  }
  // store att (overwrites this block's own q-rows / h-col slice only)
#pragma unroll
  for (int nt = 0; nt < 4; nt++) {
    float r = 1.f / LS[nt][0];
#pragma unroll
    for (int mt2 = 0; mt2 < 2; mt2++) {
      uint2 ov = make_uint2(pack2h(O[mt2][nt][0] * r, O[mt2][nt][1] * r),
                            pack2h(O[mt2][nt][2] * r, O[mt2][nt][3] * r));
      *(uint2*)(wq_att + (tbase + q0 + nt * 16 + l15) * 128 + h * 32 + mt2 * 16 + l4 * 4) = ov;
    }
  }
}

// ---------------------------------------------------------------------------
// Output projection, SWAPPED operands: D'[n][t], lane holds 4 consecutive n
// for one token -> dense uint2 stores of (att @ Wo^T + bo) into po[T][128].
// No mask, no atomics: masked slots are simply never gathered by ln_k.
__global__ __launch_bounds__(256) void proj_k(
    const u16* __restrict__ watt, const u16* __restrict__ bp, const float* __restrict__ bo,
    u16* __restrict__ po) {
  __shared__ uint4 As[64 * 16];
  int tid = threadIdx.x;
  int t0 = blockIdx.x * 64;
  {
    int r = tid >> 2, qd = tid & 3;
    const uint4* src = (const uint4*)(watt + (size_t)(t0 + r) * D_ + qd * 32);
#pragma unroll
    for (int c = 0; c < 4; c++) {
      int byteoff = (qd * 64 + c * 16) ^ ((r & 7) << 4);
      As[r * 16 + (byteoff >> 4)] = src[c];
    }
  }
  __syncthreads();
  int lane = tid & 63, wid = tid >> 6;
  int l15 = lane & 15, l4 = lane >> 4;
  int wm = wid & 1, wn = wid >> 1;
  uint2 bfrag[4][8];
  const uint2* bpp = (const uint2*)bp;
#pragma unroll
  for (int nt = 0; nt < 4; nt++) {
    int ntg = wn * 4 + nt;
#pragma unroll
    for (int ks = 0; ks < 8; ks++)
      bfrag[nt][ks] = bpp[(3 * 64 + ntg * 8 + ks) * 64 + lane];
  }
  uint2 afr[2][8];
#pragma unroll
  for (int tt = 0; tt < 2; tt++) {
    int row = wm * 32 + tt * 16 + l15;
#pragma unroll
    for (int ks = 0; ks < 8; ks++) {
      int byteoff = (ks * 32 + (l4 << 3)) ^ ((row & 7) << 4);
      afr[tt][ks] = *(const uint2*)((const char*)As + row * 256 + byteoff);
    }
  }
  // acc[nt][tt]: D'[n][t], n = wn*64+nt*16+4*l4+i, t = wm*32+tt*16+l15
  f32x4 acc[4][2];
#pragma unroll
  for (int nt = 0; nt < 4; nt++) {
    float4 bo4 = *(const float4*)(bo + wn * 64 + nt * 16 + l4 * 4);
    f32x4 bz = {bo4.x, bo4.y, bo4.z, bo4.w};
    acc[nt][0] = bz;
    acc[nt][1] = bz;
  }
#pragma unroll
  for (int kp = 0; kp < 4; kp++) {
#pragma unroll
    for (int nt = 0; nt < 4; nt++) {
      f16x8 a = cat8(bfrag[nt][2 * kp], bfrag[nt][2 * kp + 1]);
#pragma unroll
      for (int tt = 0; tt < 2; tt++) {
        f16x8 b = cat8(afr[tt][2 * kp], afr[tt][2 * kp + 1]);
        acc[nt][tt] = mfma32(a, b, acc[nt][tt]);
      }
    }
  }
#pragma unroll
  for (int tt = 0; tt < 2; tt++) {
    size_t tok = t0 + wm * 32 + tt * 16 + l15;
#pragma unroll
    for (int nt = 0; nt < 4; nt++) {
      int n0 = wn * 64 + nt * 16 + l4 * 4;
      f32x4 a = acc[nt][tt];
      uint2 pv = make_uint2(pack2h(a[0], a[1]), pack2h(a[2], a[3]));
      *(uint2*)(po + tok * D_ + n0) = pv;
    }
  }
}

// ---------------------------------------------------------------------------
// Gather-aggregate + residual + LayerNorm. Per (b,n) row: sum deg rows of po
// (fp32 accum) via the inverted index, h = x + sum/max(cnt,1), LN over D.
__global__ __launch_bounds__(256) void ln_k(
    const float* __restrict__ x, const int* __restrict__ cursor,
    const u16* __restrict__ po, const int* __restrict__ slots,
    const float* __restrict__ g, const float* __restrict__ bta, float* __restrict__ out) {
  int tid = threadIdx.x;
  int row = blockIdx.x * 8 + (tid >> 5);
  if (row >= B_ * N_) return;
  int l32 = tid & 31;
  int n = row % N_;
  int b = row / N_;
  int cnt = cursor[n];
  int deg = cnt > CAP_ ? CAP_ : cnt;
  float rc = 1.f / (float)(cnt > 1 ? cnt : 1);
  float4 a = make_float4(0.f, 0.f, 0.f, 0.f);
  const int* sl = slots + n * CAP_;
  for (int j = 0; j < deg; j++) {
    int s = sl[j];
    uint2 u = *(const uint2*)(po + ((size_t)b * PS_ + s) * D_ + l32 * 4);
    float2 a01 = __half22float2(__builtin_bit_cast(__half2, u.x));
    float2 a23 = __half22float2(__builtin_bit_cast(__half2, u.y));
    a.x += a01.x; a.y += a01.y; a.z += a23.x; a.w += a23.y;
  }
  size_t off = (size_t)row * D_ + l32 * 4;
  float4 xa = *(const float4*)(x + off);
  float4 hv = make_float4(fmaf(a.x, rc, xa.x), fmaf(a.y, rc, xa.y),
                          fmaf(a.z, rc, xa.z), fmaf(a.w, rc, xa.w));
  float s = hv.x + hv.y + hv.z + hv.w;
  float s2 = hv.x * hv.x + hv.y * hv.y + hv.z * hv.z + hv.w * hv.w;
#pragma unroll
  for (int m = 16; m >= 1; m >>= 1) {
    s += __shfl_xor(s, m);
    s2 += __shfl_xor(s2, m);
  }
  float mu = s * 0.0078125f;
  float var = s2 * 0.0078125f - mu * mu;
  float rstd = rsqrtf(var + 1e-5f);
  float4 gv = *(const float4*)(g + l32 * 4);
  float4 bv = *(const float4*)(bta + l32 * 4);
  float4 ov = make_float4((hv.x - mu) * rstd * gv.x + bv.x,
                          (hv.y - mu) * rstd * gv.y + bv.y,
                          (hv.z - mu) * rstd * gv.z + bv.z,
                          (hv.w - mu) * rstd * gv.w + bv.w);
  *(float4*)(out + off) = ov;
}

// ---------------------------------------------------------------------------
extern "C" void kernel_launch(void* const* d_in, const int* in_sizes, int n_in,
                              void* d_out, int out_size, void* d_ws, size_t ws_size,
                              hipStream_t stream) {
  const float* x   = (const float*)d_in[0];
  const float* Wq  = (const float*)d_in[1];
  const float* bq  = (const float*)d_in[2];
  const float* Wk  = (const float*)d_in[3];
  const float* bk  = (const float*)d_in[4];
  const float* Wv  = (const float*)d_in[5];
  const float* bv  = (const float*)d_in[6];
  const float* Wo  = (const float*)d_in[7];
  const float* bo  = (const float*)d_in[8];
  const float* lng = (const float*)d_in[9];
  const float* lnb = (const float*)d_in[10];
  const int* pidx  = (const int*)d_in[11];
  const void* cmask = d_in[12];
  float* out = (float*)d_out;
  char* ws = (char*)d_ws;

  u16* wsq = (u16*)(ws + OFF_Q);
  u16* wsk = (u16*)(ws + OFF_K);
  u16* wsvt = (u16*)(ws + OFF_V);
  u16* wbp = (u16*)(ws + OFF_BP);
  int* wflag  = (int*)(ws + OFF_FLAG);
  // after attn: K region -> po[T][128] fp16; V region -> cursor[N] + slots[N*CAP]
  u16* po = (u16*)(ws + OFF_K);
  int* cursor = (int*)(ws + OFF_V);
  int* slots = (int*)(ws + OFF_V + CUR_BYTES);

  hipMemsetAsync(wflag, 0, 4, stream);

  probe_mask_k<<<200, 256, 0, stream>>>((const unsigned char*)cmask, wflag);
  pack_w_k<<<64, 256, 0, stream>>>(Wq, Wk, Wv, Wo, wbp);
  qkv_k<<<1600, 256, 0, stream>>>(x, pidx, wbp, bq, bk, bv, wsq);
  attn_k<<<800, 512, 0, stream>>>(wsq, wsk, wsvt);
  // V region dead: build inverted index there (cursor doubles as cnt)
  hipMemsetAsync(cursor, 0, CUR_BYTES, stream);
  fill_k<<<200, 256, 0, stream>>>(cmask, pidx, wflag, cursor, slots);
  proj_k<<<1600, 256, 0, stream>>>(wsq, wbp, bo, po);
  ln_k<<<10241, 256, 0, stream>>>(x, cursor, po, slots, lng, lnb, out);
}